// Round 1
// baseline (3288.258 us; speedup 1.0000x reference)
//
#include <hip/hip_runtime.h>

#define GN_EPS 1e-5f

constexpr int NB   = 64;            // graphs
constexpr int ETOT = 64 * 1024 * 16; // 1048576 edges

// ---------------------------------------------------------------- edge init
__global__ void edge_init_kernel(const int* __restrict__ ei,
                                 int* __restrict__ esrc, int* __restrict__ edst) {
    int e = blockIdx.x * blockDim.x + threadIdx.x;
    if (e >= ETOT) return;
    esrc[e] = ei[e];
    edst[e] = ei[ETOT + e];
}

// ---------------------------------------------------------------- degree
__global__ void deg_init_kernel(float* __restrict__ deg, int n) {
    int i = blockIdx.x * blockDim.x + threadIdx.x;
    if (i < n) deg[i] = 1.0f;   // self loop
}

__global__ void deg_accum_kernel(const int* __restrict__ esrc, const int* __restrict__ edst,
                                 float* __restrict__ deg) {
    int e = blockIdx.x * blockDim.x + threadIdx.x;
    if (e >= ETOT) return;
    int s = esrc[e];
    if (s < 0) return;
    unsafeAtomicAdd(&deg[edst[e]], 1.0f);
}

// ---------------------------------------------------------------- GEMM  C[M,N] = A[M,K] @ W[K,N]
__global__ __launch_bounds__(256) void gemm64_kernel(const float* __restrict__ A,
                                                     const float* __restrict__ W,
                                                     float* __restrict__ C,
                                                     int M, int N, int K) {
    __shared__ float As[16][68];
    __shared__ float Bs[16][68];
    const int bm = blockIdx.x * 64;
    const int bn = blockIdx.y * 64;
    const int tid = threadIdx.x;
    const int tx = tid & 15, ty = tid >> 4;
    float acc[4][4] = {};
    for (int k0 = 0; k0 < K; k0 += 16) {
        {   // A tile: 64 rows x 16 k
            int m  = tid >> 2;
            int kk = (tid & 3) * 4;
            const float* a = A + (size_t)(bm + m) * K + k0 + kk;
#pragma unroll
            for (int i = 0; i < 4; i++) {
                int k = kk + i;
                As[k][m] = (k0 + k < K) ? a[i] : 0.0f;
            }
        }
        {   // W tile: 16 k x 64 n
#pragma unroll
            for (int i = 0; i < 4; i++) {
                int idx = tid + i * 256;
                int k = idx >> 6, n = idx & 63;
                Bs[k][n] = (k0 + k < K) ? W[(size_t)(k0 + k) * N + bn + n] : 0.0f;
            }
        }
        __syncthreads();
#pragma unroll
        for (int k = 0; k < 16; k++) {
            float a[4], b[4];
#pragma unroll
            for (int r = 0; r < 4; r++) a[r] = As[k][ty * 4 + r];
#pragma unroll
            for (int c = 0; c < 4; c++) b[c] = Bs[k][tx * 4 + c];
#pragma unroll
            for (int r = 0; r < 4; r++)
#pragma unroll
                for (int c = 0; c < 4; c++)
                    acc[r][c] += a[r] * b[c];
        }
        __syncthreads();
    }
#pragma unroll
    for (int r = 0; r < 4; r++) {
        int m = bm + ty * 4 + r;
#pragma unroll
        for (int c = 0; c < 4; c++)
            C[(size_t)m * N + bn + tx * 4 + c] = acc[r][c];
    }
}

// ---------------------------------------------------------------- agg init: out = h/deg + b
__global__ void agg_init_kernel(const float* __restrict__ h, const float* __restrict__ deg,
                                const float* __restrict__ b, float* __restrict__ out,
                                int total, int ldo) {
    int t = blockIdx.x * blockDim.x + threadIdx.x;
    if (t >= total) return;
    int v = t >> ldo;
    int f = t & ((1 << ldo) - 1);
    out[t] = h[t] / deg[v] + b[f];
}

// ---------------------------------------------------------------- edge scatter
__global__ void scatter_kernel(const int* __restrict__ esrc, const int* __restrict__ edst,
                               const float* __restrict__ deg, const float* __restrict__ h,
                               float* __restrict__ out, int total, int ldof4) {
    int t = blockIdx.x * blockDim.x + threadIdx.x;
    if (t >= total) return;
    int e  = t >> ldof4;
    int f4 = t & ((1 << ldof4) - 1);
    int s = esrc[e];
    if (s < 0) return;
    int d = edst[e];
    float norm = rsqrtf(deg[s]) * rsqrtf(deg[d]);
    int dof4 = 1 << ldof4;
    const float4 hv = reinterpret_cast<const float4*>(h)[(size_t)s * dof4 + f4];
    float* o = out + ((size_t)d * dof4 + f4) * 4;
    unsafeAtomicAdd(o + 0, hv.x * norm);
    unsafeAtomicAdd(o + 1, hv.y * norm);
    unsafeAtomicAdd(o + 2, hv.z * norm);
    unsafeAtomicAdd(o + 3, hv.w * norm);
}

// ---------------------------------------------------------------- graphnorm stats
__global__ void gn_stats_kernel(const float* __restrict__ x, const float* __restrict__ ms,
                                const float* __restrict__ w, float* __restrict__ cmean,
                                float* __restrict__ srw, int n_per, int do_) {
    int g = blockIdx.x;
    int f = threadIdx.x;          // blockDim == do_
    const float* xg = x + (size_t)g * n_per * do_;
    float s = 0.f, s2 = 0.f;
    for (int i = 0; i < n_per; i++) {
        float v = xg[(size_t)i * do_ + f];
        s += v; s2 += v * v;
    }
    float inv_n = 1.0f / (float)n_per;
    float mean = s * inv_n;
    float ex2  = s2 * inv_n;
    float m = ms[f];
    float var = ex2 - 2.f * m * mean * mean + m * m * mean * mean;
    cmean[g * do_ + f] = m * mean;
    srw[g * do_ + f]   = w[f] * rsqrtf(var + GN_EPS);
}

// ---------------------------------------------------------------- 1/||p||
__global__ void pnorm_kernel(const float* __restrict__ p, float* __restrict__ out, int do_) {
    __shared__ float red[256];
    int t = threadIdx.x;
    float v = (t < do_) ? p[t] : 0.0f;
    red[t] = v * v;
    __syncthreads();
    for (int s = 128; s; s >>= 1) {
        if (t < s) red[t] += red[t + s];
        __syncthreads();
    }
    if (t == 0) out[0] = 1.0f / sqrtf(red[0]);
}

// ---------------------------------------------------------------- graphnorm apply + relu + score
template <int DO>
__global__ __launch_bounds__(256) void gn_apply_score_kernel(
        float* __restrict__ x, const float* __restrict__ cmean, const float* __restrict__ srw,
        const float* __restrict__ bias, const float* __restrict__ p,
        const float* __restrict__ pinv, float* __restrict__ score, int n_per) {
    constexpr int V = DO / 64;
    int node = blockIdx.x * 4 + (threadIdx.x >> 6);
    int lane = threadIdx.x & 63;
    int g = node / n_per;
    float*       xr = x + (size_t)node * DO + lane * V;
    const float* cm = cmean + g * DO + lane * V;
    const float* sw = srw + g * DO + lane * V;
    const float* bb = bias + lane * V;
    const float* pp = p + lane * V;
    float dot = 0.f;
#pragma unroll
    for (int i = 0; i < V; i++) {
        float y = (xr[i] - cm[i]) * sw[i] + bb[i];
        y = fmaxf(y, 0.0f);
        xr[i] = y;
        dot += y * pp[i];
    }
#pragma unroll
    for (int off = 32; off; off >>= 1) dot += __shfl_xor(dot, off);
    if (lane == 0) score[node] = tanhf(dot * pinv[0]);
}

// ---------------------------------------------------------------- top-k (rank based, lax.top_k tie-break)
__global__ void topk_kernel(const float* __restrict__ score, int* __restrict__ mapping,
                            int* __restrict__ inv, int n_per, int k) {
    __shared__ float s[1024];
    int g = blockIdx.x;
    int i = threadIdx.x;             // blockDim == n_per
    float si = score[g * n_per + i];
    s[i] = si;
    __syncthreads();
    int rank = 0;
    for (int j = 0; j < n_per; j++) {
        float sj = s[j];
        rank += (sj > si) || (sj == si && j < i);
    }
    int old_g = g * n_per + i;
    if (rank < k) {
        int neu = g * k + rank;
        mapping[old_g] = neu;
        inv[neu] = old_g;
    } else {
        mapping[old_g] = -1;
    }
}

// ---------------------------------------------------------------- permute + scale by score
__global__ void permute_scale_kernel(const float* __restrict__ x, const int* __restrict__ inv,
                                     const float* __restrict__ score, float* __restrict__ xn,
                                     int total, int ldof4) {
    int t = blockIdx.x * blockDim.x + threadIdx.x;
    if (t >= total) return;
    int node = t >> ldof4;
    int f4   = t & ((1 << ldof4) - 1);
    int dof4 = 1 << ldof4;
    int old = inv[node];
    float sc = score[old];
    float4 v = reinterpret_cast<const float4*>(x)[(size_t)old * dof4 + f4];
    float4 o = {v.x * sc, v.y * sc, v.z * sc, v.w * sc};
    reinterpret_cast<float4*>(xn)[t] = o;
}

// ---------------------------------------------------------------- edge remap
__global__ void remap_edges_kernel(int* __restrict__ esrc, int* __restrict__ edst,
                                   const int* __restrict__ mapping) {
    int e = blockIdx.x * blockDim.x + threadIdx.x;
    if (e >= ETOT) return;
    int s = esrc[e];
    if (s < 0) return;
    int ns = mapping[s];
    int nd = mapping[edst[e]];
    if (ns >= 0 && nd >= 0) { esrc[e] = ns; edst[e] = nd; }
    else                    { esrc[e] = -1; edst[e] = 0;  }
}

// ---------------------------------------------------------------- final mean/max pool
__global__ void pool_kernel(const float* __restrict__ x, float* __restrict__ out, int n_per) {
    int g = blockIdx.x;
    int f = threadIdx.x;             // 256 threads
    const float* xg = x + (size_t)g * n_per * 256;
    float s = 0.f, mx = -INFINITY;
    for (int i = 0; i < n_per; i++) {
        float v = xg[(size_t)i * 256 + f];
        s += v;
        mx = fmaxf(mx, v);
    }
    out[g * 512 + f]       = s / (float)n_per;
    out[g * 512 + 256 + f] = mx;
}

// ================================================================ host
static inline int cdiv_h(int a, int b) { return (a + b - 1) / b; }

extern "C" void kernel_launch(void* const* d_in, const int* in_sizes, int n_in,
                              void* d_out, int out_size, void* d_ws, size_t ws_size,
                              hipStream_t stream) {
    (void)in_sizes; (void)n_in; (void)out_size; (void)ws_size;

    const float* x_in = (const float*)d_in[0];
    const int*   ei   = (const int*)d_in[1];
    // d_in[2] = batch (unused, equal-sized graphs)
    const float* Wm[3]  = {(const float*)d_in[3],  (const float*)d_in[9],  (const float*)d_in[15]};
    const float* bv[3]  = {(const float*)d_in[4],  (const float*)d_in[10], (const float*)d_in[16]};
    const float* gnw[3] = {(const float*)d_in[5],  (const float*)d_in[11], (const float*)d_in[17]};
    const float* gnb[3] = {(const float*)d_in[6],  (const float*)d_in[12], (const float*)d_in[18]};
    const float* gnm[3] = {(const float*)d_in[7],  (const float*)d_in[13], (const float*)d_in[19]};
    const float* pv[3]  = {(const float*)d_in[8],  (const float*)d_in[14], (const float*)d_in[20]};

    // workspace carve
    size_t off = 0;
    auto alloc = [&](size_t bytes) {
        void* p = (char*)d_ws + off;
        off += (bytes + 255) & ~(size_t)255;
        return p;
    };
    float* X1    = (float*)alloc((size_t)65536 * 128 * 4);
    float* H     = (float*)alloc((size_t)65536 * 128 * 4);
    float* X2    = (float*)alloc((size_t)32768 * 128 * 4);
    int*   esrc  = (int*)alloc((size_t)ETOT * 4);
    int*   edst  = (int*)alloc((size_t)ETOT * 4);
    float* deg   = (float*)alloc(65536 * 4);
    float* score = (float*)alloc(65536 * 4);
    int*   mapping = (int*)alloc(65536 * 4);
    int*   inv   = (int*)alloc(32768 * 4);
    float* cmean = (float*)alloc(64 * 256 * 4);
    float* srw   = (float*)alloc(64 * 256 * 4);
    float* pinv  = (float*)alloc(256);

    const int nper[4] = {1024, 512, 256, 128};
    const int din[3]  = {100, 128, 128};
    const int dof[3]  = {128, 128, 256};

    edge_init_kernel<<<cdiv_h(ETOT, 256), 256, 0, stream>>>(ei, esrc, edst);

    for (int L = 0; L < 3; L++) {
        const int n   = NB * nper[L];
        const int k   = nper[L + 1];
        const int nn  = NB * k;
        const int D   = dof[L];
        const int ldo = (D == 128) ? 7 : 8;
        const int dof4 = D / 4;
        const int ldof4 = (dof4 == 32) ? 5 : 6;
        const float* xin = (L == 0) ? x_in : X2;

        // degree
        deg_init_kernel<<<cdiv_h(n, 256), 256, 0, stream>>>(deg, n);
        deg_accum_kernel<<<cdiv_h(ETOT, 256), 256, 0, stream>>>(esrc, edst, deg);

        // h = x @ W
        gemm64_kernel<<<dim3(n / 64, D / 64), 256, 0, stream>>>(xin, Wm[L], H, n, D, din[L]);

        // agg = h/deg + b, then scatter-add over edges
        agg_init_kernel<<<cdiv_h(n * D, 256), 256, 0, stream>>>(H, deg, bv[L], X1, n * D, ldo);
        scatter_kernel<<<cdiv_h(ETOT * dof4, 256), 256, 0, stream>>>(esrc, edst, deg, H, X1,
                                                                     ETOT * dof4, ldof4);

        // graphnorm stats + apply + relu + score
        gn_stats_kernel<<<NB, D, 0, stream>>>(X1, gnm[L], gnw[L], cmean, srw, nper[L], D);
        pnorm_kernel<<<1, 256, 0, stream>>>(pv[L], pinv, D);
        if (D == 128)
            gn_apply_score_kernel<128><<<n / 4, 256, 0, stream>>>(X1, cmean, srw, gnb[L],
                                                                  pv[L], pinv, score, nper[L]);
        else
            gn_apply_score_kernel<256><<<n / 4, 256, 0, stream>>>(X1, cmean, srw, gnb[L],
                                                                  pv[L], pinv, score, nper[L]);

        // top-k pooling
        topk_kernel<<<NB, nper[L], 0, stream>>>(score, mapping, inv, nper[L], k);
        permute_scale_kernel<<<cdiv_h(nn * dof4, 256), 256, 0, stream>>>(X1, inv, score, X2,
                                                                         nn * dof4, ldof4);
        remap_edges_kernel<<<cdiv_h(ETOT, 256), 256, 0, stream>>>(esrc, edst, mapping);
    }

    // final mean/max pool -> [64, 512]
    pool_kernel<<<NB, 256, 0, stream>>>(X2, (float*)d_out, nper[3]);
}

// Round 5
// 541.664 us; speedup vs baseline: 6.0707x; 6.0707x over previous
//
#include <hip/hip_runtime.h>

#define GN_EPS 1e-5f

constexpr int NB   = 64;             // graphs
constexpr int ETOT = 64 * 1024 * 16; // 1048576 edges

// ---------------------------------------------------------------- edge init
__global__ void edge_init_kernel(const int* __restrict__ ei,
                                 int* __restrict__ esrc, int* __restrict__ edst) {
    int e = blockIdx.x * blockDim.x + threadIdx.x;
    if (e >= ETOT) return;
    esrc[e] = ei[e];
    edst[e] = ei[ETOT + e];
}

// ---------------------------------------------------------------- in-degree count (int)
__global__ void deg_count_kernel(const int* __restrict__ esrc, const int* __restrict__ edst,
                                 int* __restrict__ cnt) {
    int e = blockIdx.x * blockDim.x + threadIdx.x;
    if (e >= ETOT) return;
    int s = esrc[e];
    if (s < 0) return;
    atomicAdd(&cnt[edst[e]], 1);
}

// ---------------------------------------------------------------- 2-level exclusive scan
__global__ void scan1_kernel(const int* __restrict__ cnt, int* __restrict__ offs,
                             int* __restrict__ blksum, int n) {
    __shared__ int s[256];
    int t = threadIdx.x;
    int i = blockIdx.x * 256 + t;
    int v = (i < n) ? cnt[i] : 0;
    s[t] = v;
    __syncthreads();
    for (int d = 1; d < 256; d <<= 1) {
        int x = (t >= d) ? s[t - d] : 0;
        __syncthreads();
        s[t] += x;
        __syncthreads();
    }
    if (i < n) offs[i] = s[t] - v;              // exclusive
    if (t == 255) blksum[blockIdx.x] = s[255];
}

__global__ void scan2_kernel(int* __restrict__ blksum, int nb) {
    __shared__ int s[256];
    int t = threadIdx.x;
    int v = (t < nb) ? blksum[t] : 0;
    s[t] = v;
    __syncthreads();
    for (int d = 1; d < 256; d <<= 1) {
        int x = (t >= d) ? s[t - d] : 0;
        __syncthreads();
        s[t] += x;
        __syncthreads();
    }
    if (t < nb) blksum[t] = s[t] - v;           // exclusive over block sums
}

__global__ void scan3_kernel(int* __restrict__ offs, const int* __restrict__ blksum,
                             int* __restrict__ fillpos, int n) {
    int i = blockIdx.x * 256 + threadIdx.x;
    if (i >= n) return;
    int o = offs[i] + blksum[blockIdx.x];
    offs[i] = o;
    fillpos[i] = o;
}

// ---------------------------------------------------------------- CSR fill (src + precomputed norm)
__global__ void csr_fill_kernel(const int* __restrict__ esrc, const int* __restrict__ edst,
                                const int* __restrict__ cnt, int* __restrict__ fillpos,
                                int* __restrict__ csr_src, float* __restrict__ csr_norm) {
    int e = blockIdx.x * blockDim.x + threadIdx.x;
    if (e >= ETOT) return;
    int s = esrc[e];
    if (s < 0) return;
    int d = edst[e];
    int pos = atomicAdd(&fillpos[d], 1);
    csr_src[pos] = s;
    csr_norm[pos] = rsqrtf(1.0f + (float)cnt[s]) * rsqrtf(1.0f + (float)cnt[d]);
}

// ---------------------------------------------------------------- GEMM  C[M,N] = A[M,K] @ W[K,N]
__global__ __launch_bounds__(256) void gemm64_kernel(const float* __restrict__ A,
                                                     const float* __restrict__ W,
                                                     float* __restrict__ C,
                                                     int M, int N, int K) {
    __shared__ float As[16][68];
    __shared__ float Bs[16][68];
    const int bm = blockIdx.x * 64;
    const int bn = blockIdx.y * 64;
    const int tid = threadIdx.x;
    const int tx = tid & 15, ty = tid >> 4;
    float acc[4][4] = {};
    for (int k0 = 0; k0 < K; k0 += 16) {
        {   // A tile: 64 rows x 16 k
            int m  = tid >> 2;
            int kk = (tid & 3) * 4;
            const float* a = A + (size_t)(bm + m) * K + k0 + kk;
#pragma unroll
            for (int i = 0; i < 4; i++) {
                int k = kk + i;
                As[k][m] = (k0 + k < K) ? a[i] : 0.0f;
            }
        }
        {   // W tile: 16 k x 64 n
#pragma unroll
            for (int i = 0; i < 4; i++) {
                int idx = tid + i * 256;
                int k = idx >> 6, n = idx & 63;
                Bs[k][n] = (k0 + k < K) ? W[(size_t)(k0 + k) * N + bn + n] : 0.0f;
            }
        }
        __syncthreads();
#pragma unroll
        for (int k = 0; k < 16; k++) {
            float a[4], b[4];
#pragma unroll
            for (int r = 0; r < 4; r++) a[r] = As[k][ty * 4 + r];
#pragma unroll
            for (int c = 0; c < 4; c++) b[c] = Bs[k][tx * 4 + c];
#pragma unroll
            for (int r = 0; r < 4; r++)
#pragma unroll
                for (int c = 0; c < 4; c++)
                    acc[r][c] += a[r] * b[c];
        }
        __syncthreads();
    }
#pragma unroll
    for (int r = 0; r < 4; r++) {
        int m = bm + ty * 4 + r;
#pragma unroll
        for (int c = 0; c < 4; c++)
            C[(size_t)m * N + bn + tx * 4 + c] = acc[r][c];
    }
}

// ---------------------------------------------------------------- CSR gather: out = sum h[src]*norm + h/deg + b
template <int D4>   // 32 (D=128) or 64 (D=256)
__global__ __launch_bounds__(256) void gather_kernel(
        const float* __restrict__ h, const int* __restrict__ cnt,
        const int* __restrict__ offs, const int* __restrict__ csr_src,
        const float* __restrict__ csr_norm, const float* __restrict__ b,
        float* __restrict__ out, int n) {
    constexpr int NPB = 256 / D4;
    int v  = blockIdx.x * NPB + threadIdx.x / D4;
    int f4 = threadIdx.x % D4;
    if (v >= n) return;
    const float4* h4 = reinterpret_cast<const float4*>(h);
    int st = offs[v];
    int c  = cnt[v];
    float4 acc = {0.f, 0.f, 0.f, 0.f};
    int j = 0;
    for (; j + 2 <= c; j += 2) {
        int   s0 = csr_src[st + j],     s1 = csr_src[st + j + 1];
        float n0 = csr_norm[st + j],    n1 = csr_norm[st + j + 1];
        float4 h0 = h4[(size_t)s0 * D4 + f4];
        float4 h1 = h4[(size_t)s1 * D4 + f4];
        acc.x += h0.x * n0 + h1.x * n1;
        acc.y += h0.y * n0 + h1.y * n1;
        acc.z += h0.z * n0 + h1.z * n1;
        acc.w += h0.w * n0 + h1.w * n1;
    }
    if (j < c) {
        int s0 = csr_src[st + j];
        float n0 = csr_norm[st + j];
        float4 h0 = h4[(size_t)s0 * D4 + f4];
        acc.x += h0.x * n0; acc.y += h0.y * n0; acc.z += h0.z * n0; acc.w += h0.w * n0;
    }
    float invd = 1.0f / (1.0f + (float)c);
    float4 hv = h4[(size_t)v * D4 + f4];
    float4 bb = reinterpret_cast<const float4*>(b)[f4];
    float4 o;
    o.x = acc.x + hv.x * invd + bb.x;
    o.y = acc.y + hv.y * invd + bb.y;
    o.z = acc.z + hv.z * invd + bb.z;
    o.w = acc.w + hv.w * invd + bb.w;
    reinterpret_cast<float4*>(out)[(size_t)v * D4 + f4] = o;
}

// ---------------------------------------------------------------- graphnorm partial sums (chunked)
template <int D4>   // 32 or 64
__global__ __launch_bounds__(256) void gn_partial_kernel(
        const float* __restrict__ x, float* __restrict__ sum1, float* __restrict__ sum2,
        int n_per) {
    constexpr int GROUPS = 256 / D4;
    __shared__ float4 l1[256];
    __shared__ float4 l2[256];
    int g = blockIdx.x >> 3;          // graph
    int ch = blockIdx.x & 7;          // node chunk (8 chunks)
    int f4 = threadIdx.x % D4;
    int grp = threadIdx.x / D4;
    int chunk = n_per / 8;
    int base = g * n_per + ch * chunk;
    const float4* x4 = reinterpret_cast<const float4*>(x);
    float4 s1 = {0.f, 0.f, 0.f, 0.f}, s2 = {0.f, 0.f, 0.f, 0.f};
    for (int i = grp; i < chunk; i += GROUPS) {
        float4 v = x4[(size_t)(base + i) * D4 + f4];
        s1.x += v.x; s1.y += v.y; s1.z += v.z; s1.w += v.w;
        s2.x += v.x * v.x; s2.y += v.y * v.y; s2.z += v.z * v.z; s2.w += v.w * v.w;
    }
    int t = threadIdx.x;
    l1[t] = s1; l2[t] = s2;
    __syncthreads();
    for (int str = 128; str >= D4; str >>= 1) {
        if (t < str) {
            float4 a = l1[t + str], b2 = l2[t + str];
            l1[t].x += a.x; l1[t].y += a.y; l1[t].z += a.z; l1[t].w += a.w;
            l2[t].x += b2.x; l2[t].y += b2.y; l2[t].z += b2.z; l2[t].w += b2.w;
        }
        __syncthreads();
    }
    if (t < D4) {
        float4 a = l1[t], b2 = l2[t];
        float* p1 = sum1 + g * (D4 * 4) + t * 4;
        float* p2 = sum2 + g * (D4 * 4) + t * 4;
        unsafeAtomicAdd(p1 + 0, a.x); unsafeAtomicAdd(p1 + 1, a.y);
        unsafeAtomicAdd(p1 + 2, a.z); unsafeAtomicAdd(p1 + 3, a.w);
        unsafeAtomicAdd(p2 + 0, b2.x); unsafeAtomicAdd(p2 + 1, b2.y);
        unsafeAtomicAdd(p2 + 2, b2.z); unsafeAtomicAdd(p2 + 3, b2.w);
    }
}

__global__ void gn_final_kernel(const float* __restrict__ sum1, const float* __restrict__ sum2,
                                const float* __restrict__ ms, const float* __restrict__ w,
                                float* __restrict__ cmean, float* __restrict__ srw,
                                int n_per, int D, int total) {
    int t = blockIdx.x * blockDim.x + threadIdx.x;
    if (t >= total) return;
    int f = t % D;
    float inv_n = 1.0f / (float)n_per;
    float mean = sum1[t] * inv_n;
    float ex2  = sum2[t] * inv_n;
    float m = ms[f];
    float var = ex2 - 2.f * m * mean * mean + m * m * mean * mean;
    cmean[t] = m * mean;
    srw[t]   = w[f] * rsqrtf(var + GN_EPS);
}

// ---------------------------------------------------------------- 1/||p||
__global__ void pnorm_kernel(const float* __restrict__ p, float* __restrict__ out, int do_) {
    __shared__ float red[256];
    int t = threadIdx.x;
    float v = (t < do_) ? p[t] : 0.0f;
    red[t] = v * v;
    __syncthreads();
    for (int s = 128; s; s >>= 1) {
        if (t < s) red[t] += red[t + s];
        __syncthreads();
    }
    if (t == 0) out[0] = 1.0f / sqrtf(red[0]);
}

// ---------------------------------------------------------------- graphnorm apply + relu + score
template <int DO>
__global__ __launch_bounds__(256) void gn_apply_score_kernel(
        float* __restrict__ x, const float* __restrict__ cmean, const float* __restrict__ srw,
        const float* __restrict__ bias, const float* __restrict__ p,
        const float* __restrict__ pinv, float* __restrict__ score, int n_per) {
    constexpr int V = DO / 64;
    int node = blockIdx.x * 4 + (threadIdx.x >> 6);
    int lane = threadIdx.x & 63;
    int g = node / n_per;
    float*       xr = x + (size_t)node * DO + lane * V;
    const float* cm = cmean + g * DO + lane * V;
    const float* sw = srw + g * DO + lane * V;
    const float* bb = bias + lane * V;
    const float* pp = p + lane * V;
    float dot = 0.f;
#pragma unroll
    for (int i = 0; i < V; i++) {
        float y = (xr[i] - cm[i]) * sw[i] + bb[i];
        y = fmaxf(y, 0.0f);
        xr[i] = y;
        dot += y * pp[i];
    }
#pragma unroll
    for (int off = 32; off; off >>= 1) dot += __shfl_xor(dot, off);
    if (lane == 0) score[node] = tanhf(dot * pinv[0]);
}

// ---------------------------------------------------------------- top-k (rank based, lax.top_k tie-break)
__global__ void topk_kernel(const float* __restrict__ score, int* __restrict__ mapping,
                            int* __restrict__ inv, int n_per, int k) {
    __shared__ float s[1024];
    int g = blockIdx.x;
    int i = threadIdx.x;             // blockDim == n_per
    float si = score[g * n_per + i];
    s[i] = si;
    __syncthreads();
    int rank = 0;
    for (int j = 0; j < n_per; j++) {
        float sj = s[j];
        rank += (sj > si) || (sj == si && j < i);
    }
    int old_g = g * n_per + i;
    if (rank < k) {
        int neu = g * k + rank;
        mapping[old_g] = neu;
        inv[neu] = old_g;
    } else {
        mapping[old_g] = -1;
    }
}

// ---------------------------------------------------------------- permute + scale by score
__global__ void permute_scale_kernel(const float* __restrict__ x, const int* __restrict__ inv,
                                     const float* __restrict__ score, float* __restrict__ xn,
                                     int total, int ldof4) {
    int t = blockIdx.x * blockDim.x + threadIdx.x;
    if (t >= total) return;
    int node = t >> ldof4;
    int f4   = t & ((1 << ldof4) - 1);
    int dof4 = 1 << ldof4;
    int old = inv[node];
    float sc = score[old];
    float4 v = reinterpret_cast<const float4*>(x)[(size_t)old * dof4 + f4];
    float4 o = {v.x * sc, v.y * sc, v.z * sc, v.w * sc};
    reinterpret_cast<float4*>(xn)[t] = o;
}

// ---------------------------------------------------------------- edge remap
__global__ void remap_edges_kernel(int* __restrict__ esrc, int* __restrict__ edst,
                                   const int* __restrict__ mapping) {
    int e = blockIdx.x * blockDim.x + threadIdx.x;
    if (e >= ETOT) return;
    int s = esrc[e];
    if (s < 0) return;
    int ns = mapping[s];
    int nd = mapping[edst[e]];
    if (ns >= 0 && nd >= 0) { esrc[e] = ns; edst[e] = nd; }
    else                    { esrc[e] = -1; edst[e] = 0;  }
}

// ---------------------------------------------------------------- final mean/max pool
__global__ void pool_kernel(const float* __restrict__ x, float* __restrict__ out, int n_per) {
    int g = blockIdx.x;
    int f = threadIdx.x;             // 256 threads
    const float* xg = x + (size_t)g * n_per * 256;
    float s = 0.f, mx = -INFINITY;
    for (int i = 0; i < n_per; i++) {
        float v = xg[(size_t)i * 256 + f];
        s += v;
        mx = fmaxf(mx, v);
    }
    out[g * 512 + f]       = s / (float)n_per;
    out[g * 512 + 256 + f] = mx;
}

// ================================================================ host
static inline int cdiv_h(int a, int b) { return (a + b - 1) / b; }

extern "C" void kernel_launch(void* const* d_in, const int* in_sizes, int n_in,
                              void* d_out, int out_size, void* d_ws, size_t ws_size,
                              hipStream_t stream) {
    (void)in_sizes; (void)n_in; (void)out_size; (void)ws_size;

    const float* x_in = (const float*)d_in[0];
    const int*   ei   = (const int*)d_in[1];
    // d_in[2] = batch (unused, equal-sized graphs)
    const float* Wm[3]  = {(const float*)d_in[3],  (const float*)d_in[9],  (const float*)d_in[15]};
    const float* bv[3]  = {(const float*)d_in[4],  (const float*)d_in[10], (const float*)d_in[16]};
    const float* gnw[3] = {(const float*)d_in[5],  (const float*)d_in[11], (const float*)d_in[17]};
    const float* gnb[3] = {(const float*)d_in[6],  (const float*)d_in[12], (const float*)d_in[18]};
    const float* gnm[3] = {(const float*)d_in[7],  (const float*)d_in[13], (const float*)d_in[19]};
    const float* pv[3]  = {(const float*)d_in[8],  (const float*)d_in[14], (const float*)d_in[20]};

    // workspace carve
    size_t off = 0;
    auto alloc = [&](size_t bytes) {
        void* p = (char*)d_ws + off;
        off += (bytes + 255) & ~(size_t)255;
        return p;
    };
    float* X1      = (float*)alloc((size_t)65536 * 128 * 4);
    float* H       = (float*)alloc((size_t)65536 * 128 * 4);
    float* X2      = (float*)alloc((size_t)32768 * 128 * 4);
    int*   esrc    = (int*)alloc((size_t)ETOT * 4);
    int*   edst    = (int*)alloc((size_t)ETOT * 4);
    int*   csr_src = (int*)alloc((size_t)ETOT * 4);
    float* csr_nrm = (float*)alloc((size_t)ETOT * 4);
    int*   cnt     = (int*)alloc(65536 * 4);
    int*   offs    = (int*)alloc(65536 * 4);
    int*   fillpos = (int*)alloc(65536 * 4);
    int*   blksum  = (int*)alloc(256 * 4);
    float* score   = (float*)alloc(65536 * 4);
    int*   mapping = (int*)alloc(65536 * 4);
    int*   inv     = (int*)alloc(32768 * 4);
    float* sum1    = (float*)alloc(64 * 256 * 4);
    float* sum2    = (float*)alloc(64 * 256 * 4);
    float* cmean   = (float*)alloc(64 * 256 * 4);
    float* srw     = (float*)alloc(64 * 256 * 4);
    float* pinv    = (float*)alloc(256);

    const int nper[4] = {1024, 512, 256, 128};
    const int din[3]  = {100, 128, 128};
    const int dof[3]  = {128, 128, 256};

    edge_init_kernel<<<cdiv_h(ETOT, 256), 256, 0, stream>>>(ei, esrc, edst);

    for (int L = 0; L < 3; L++) {
        const int n    = NB * nper[L];
        const int k    = nper[L + 1];
        const int nn   = NB * k;
        const int D    = dof[L];
        const int dof4 = D / 4;
        const int ldof4 = (dof4 == 32) ? 5 : 6;
        const float* xin = (L == 0) ? x_in : X2;
        const int nblk = n / 256;

        // ---- in-degree counts + CSR build
        hipMemsetAsync(cnt, 0, n * sizeof(int), stream);
        deg_count_kernel<<<cdiv_h(ETOT, 256), 256, 0, stream>>>(esrc, edst, cnt);
        scan1_kernel<<<nblk, 256, 0, stream>>>(cnt, offs, blksum, n);
        scan2_kernel<<<1, 256, 0, stream>>>(blksum, nblk);
        scan3_kernel<<<nblk, 256, 0, stream>>>(offs, blksum, fillpos, n);
        csr_fill_kernel<<<cdiv_h(ETOT, 256), 256, 0, stream>>>(esrc, edst, cnt, fillpos,
                                                               csr_src, csr_nrm);

        // ---- h = x @ W
        gemm64_kernel<<<dim3(n / 64, D / 64), 256, 0, stream>>>(xin, Wm[L], H, n, D, din[L]);

        // ---- fused aggregate: X1 = gather + h/deg + b
        if (dof4 == 32)
            gather_kernel<32><<<cdiv_h(n, 8), 256, 0, stream>>>(H, cnt, offs, csr_src, csr_nrm,
                                                                bv[L], X1, n);
        else
            gather_kernel<64><<<cdiv_h(n, 4), 256, 0, stream>>>(H, cnt, offs, csr_src, csr_nrm,
                                                                bv[L], X1, n);

        // ---- graphnorm stats
        hipMemsetAsync(sum1, 0, NB * D * sizeof(float), stream);
        hipMemsetAsync(sum2, 0, NB * D * sizeof(float), stream);
        if (dof4 == 32)
            gn_partial_kernel<32><<<NB * 8, 256, 0, stream>>>(X1, sum1, sum2, nper[L]);
        else
            gn_partial_kernel<64><<<NB * 8, 256, 0, stream>>>(X1, sum1, sum2, nper[L]);
        gn_final_kernel<<<cdiv_h(NB * D, 256), 256, 0, stream>>>(sum1, sum2, gnm[L], gnw[L],
                                                                 cmean, srw, nper[L], D, NB * D);
        pnorm_kernel<<<1, 256, 0, stream>>>(pv[L], pinv, D);
        if (D == 128)
            gn_apply_score_kernel<128><<<n / 4, 256, 0, stream>>>(X1, cmean, srw, gnb[L],
                                                                  pv[L], pinv, score, nper[L]);
        else
            gn_apply_score_kernel<256><<<n / 4, 256, 0, stream>>>(X1, cmean, srw, gnb[L],
                                                                  pv[L], pinv, score, nper[L]);

        // ---- top-k pooling
        topk_kernel<<<NB, nper[L], 0, stream>>>(score, mapping, inv, nper[L], k);
        permute_scale_kernel<<<cdiv_h(nn * dof4, 256), 256, 0, stream>>>(X1, inv, score, X2,
                                                                         nn * dof4, ldof4);
        remap_edges_kernel<<<cdiv_h(ETOT, 256), 256, 0, stream>>>(esrc, edst, mapping);
    }

    // final mean/max pool -> [64, 512]
    pool_kernel<<<NB, 256, 0, stream>>>(X2, (float*)d_out, nper[3]);
}

// Round 6
// 520.095 us; speedup vs baseline: 6.3224x; 1.0415x over previous
//
#include <hip/hip_runtime.h>

#define GN_EPS 1e-5f

constexpr int NB   = 64;             // graphs
constexpr int ETOT = 64 * 1024 * 16; // 1048576 edges

// ---------------------------------------------------------------- edge init
__global__ void edge_init_kernel(const int* __restrict__ ei,
                                 int* __restrict__ esrc, int* __restrict__ edst) {
    int e = blockIdx.x * blockDim.x + threadIdx.x;
    if (e >= ETOT) return;
    esrc[e] = ei[e];
    edst[e] = ei[ETOT + e];
}

// ---------------------------------------------------------------- in-degree count (int)
__global__ void deg_count_kernel(const int* __restrict__ esrc, const int* __restrict__ edst,
                                 int* __restrict__ cnt) {
    int e = blockIdx.x * blockDim.x + threadIdx.x;
    if (e >= ETOT) return;
    int s = esrc[e];
    if (s < 0) return;
    atomicAdd(&cnt[edst[e]], 1);
}

// ---------------------------------------------------------------- 2-level exclusive scan
__global__ void scan1_kernel(const int* __restrict__ cnt, int* __restrict__ offs,
                             int* __restrict__ blksum, int n) {
    __shared__ int s[256];
    int t = threadIdx.x;
    int i = blockIdx.x * 256 + t;
    int v = (i < n) ? cnt[i] : 0;
    s[t] = v;
    __syncthreads();
    for (int d = 1; d < 256; d <<= 1) {
        int x = (t >= d) ? s[t - d] : 0;
        __syncthreads();
        s[t] += x;
        __syncthreads();
    }
    if (i < n) offs[i] = s[t] - v;              // exclusive
    if (t == 255) blksum[blockIdx.x] = s[255];
}

__global__ void scan2_kernel(int* __restrict__ blksum, int nb) {
    __shared__ int s[256];
    int t = threadIdx.x;
    int v = (t < nb) ? blksum[t] : 0;
    s[t] = v;
    __syncthreads();
    for (int d = 1; d < 256; d <<= 1) {
        int x = (t >= d) ? s[t - d] : 0;
        __syncthreads();
        s[t] += x;
        __syncthreads();
    }
    if (t < nb) blksum[t] = s[t] - v;           // exclusive over block sums
}

__global__ void scan3_kernel(int* __restrict__ offs, const int* __restrict__ blksum,
                             int* __restrict__ fillpos, int n) {
    int i = blockIdx.x * 256 + threadIdx.x;
    if (i >= n) return;
    int o = offs[i] + blksum[blockIdx.x];
    offs[i] = o;
    fillpos[i] = o;
}

// ---------------------------------------------------------------- CSR fill (src + precomputed norm)
__global__ void csr_fill_kernel(const int* __restrict__ esrc, const int* __restrict__ edst,
                                const int* __restrict__ cnt, int* __restrict__ fillpos,
                                int* __restrict__ csr_src, float* __restrict__ csr_norm) {
    int e = blockIdx.x * blockDim.x + threadIdx.x;
    if (e >= ETOT) return;
    int s = esrc[e];
    if (s < 0) return;
    int d = edst[e];
    int pos = atomicAdd(&fillpos[d], 1);
    csr_src[pos] = s;
    csr_norm[pos] = rsqrtf(1.0f + (float)cnt[s]) * rsqrtf(1.0f + (float)cnt[d]);
}

// ---------------------------------------------------------------- GEMM  C[M,N] = A[M,K] @ W[K,N]
__global__ __launch_bounds__(256) void gemm64_kernel(const float* __restrict__ A,
                                                     const float* __restrict__ W,
                                                     float* __restrict__ C,
                                                     int M, int N, int K) {
    __shared__ float As[16][68];
    __shared__ float Bs[16][68];
    const int bm = blockIdx.x * 64;
    const int bn = blockIdx.y * 64;
    const int tid = threadIdx.x;
    const int tx = tid & 15, ty = tid >> 4;
    float acc[4][4] = {};
    for (int k0 = 0; k0 < K; k0 += 16) {
        {   // A tile: 64 rows x 16 k
            int m  = tid >> 2;
            int kk = (tid & 3) * 4;
            const float* a = A + (size_t)(bm + m) * K + k0 + kk;
#pragma unroll
            for (int i = 0; i < 4; i++) {
                int k = kk + i;
                As[k][m] = (k0 + k < K) ? a[i] : 0.0f;
            }
        }
        {   // W tile: 16 k x 64 n
#pragma unroll
            for (int i = 0; i < 4; i++) {
                int idx = tid + i * 256;
                int k = idx >> 6, n = idx & 63;
                Bs[k][n] = (k0 + k < K) ? W[(size_t)(k0 + k) * N + bn + n] : 0.0f;
            }
        }
        __syncthreads();
#pragma unroll
        for (int k = 0; k < 16; k++) {
            float a[4], b[4];
#pragma unroll
            for (int r = 0; r < 4; r++) a[r] = As[k][ty * 4 + r];
#pragma unroll
            for (int c = 0; c < 4; c++) b[c] = Bs[k][tx * 4 + c];
#pragma unroll
            for (int r = 0; r < 4; r++)
#pragma unroll
                for (int c = 0; c < 4; c++)
                    acc[r][c] += a[r] * b[c];
        }
        __syncthreads();
    }
#pragma unroll
    for (int r = 0; r < 4; r++) {
        int m = bm + ty * 4 + r;
#pragma unroll
        for (int c = 0; c < 4; c++)
            C[(size_t)m * N + bn + tx * 4 + c] = acc[r][c];
    }
}

// ---------------------------------------------------------------- CSR gather: out = sum h[src]*norm + h/deg + b
// XCD-affine swizzle: all blocks of one graph land on one XCD (L2 locality for h slab).
template <int D4>   // 32 (D=128) or 64 (D=256)
__global__ __launch_bounds__(256) void gather_kernel(
        const float* __restrict__ h, const int* __restrict__ cnt,
        const int* __restrict__ offs, const int* __restrict__ csr_src,
        const float* __restrict__ csr_norm, const float* __restrict__ b,
        float* __restrict__ out, int n, int bpg) {
    constexpr int NPB = 256 / D4;
    // graph-affine block swizzle: xcd = bid&7 stays fixed per graph
    int bid   = blockIdx.x;
    int xcd   = bid & 7;
    int slot  = bid >> 3;
    int graph = xcd + 8 * (slot / bpg);
    int local = slot % bpg;
    int vb    = graph * bpg + local;

    int v  = vb * NPB + threadIdx.x / D4;
    int f4 = threadIdx.x % D4;
    if (v >= n) return;
    const float4* h4 = reinterpret_cast<const float4*>(h);
    int st = offs[v];
    int c  = cnt[v];
    float4 acc = {0.f, 0.f, 0.f, 0.f};
    int j = 0;
    for (; j + 2 <= c; j += 2) {
        int   s0 = csr_src[st + j],     s1 = csr_src[st + j + 1];
        float n0 = csr_norm[st + j],    n1 = csr_norm[st + j + 1];
        float4 h0 = h4[(size_t)s0 * D4 + f4];
        float4 h1 = h4[(size_t)s1 * D4 + f4];
        acc.x += h0.x * n0 + h1.x * n1;
        acc.y += h0.y * n0 + h1.y * n1;
        acc.z += h0.z * n0 + h1.z * n1;
        acc.w += h0.w * n0 + h1.w * n1;
    }
    if (j < c) {
        int s0 = csr_src[st + j];
        float n0 = csr_norm[st + j];
        float4 h0 = h4[(size_t)s0 * D4 + f4];
        acc.x += h0.x * n0; acc.y += h0.y * n0; acc.z += h0.z * n0; acc.w += h0.w * n0;
    }
    float invd = 1.0f / (1.0f + (float)c);
    float4 hv = h4[(size_t)v * D4 + f4];
    float4 bb = reinterpret_cast<const float4*>(b)[f4];
    float4 o;
    o.x = acc.x + hv.x * invd + bb.x;
    o.y = acc.y + hv.y * invd + bb.y;
    o.z = acc.z + hv.z * invd + bb.z;
    o.w = acc.w + hv.w * invd + bb.w;
    reinterpret_cast<float4*>(out)[(size_t)v * D4 + f4] = o;
}

// ---------------------------------------------------------------- graphnorm partial sums (chunked)
template <int D4>   // 32 or 64
__global__ __launch_bounds__(256) void gn_partial_kernel(
        const float* __restrict__ x, float* __restrict__ sum1, float* __restrict__ sum2,
        int n_per) {
    constexpr int GROUPS = 256 / D4;
    __shared__ float4 l1[256];
    __shared__ float4 l2[256];
    int g = blockIdx.x >> 3;          // graph
    int ch = blockIdx.x & 7;          // node chunk (8 chunks)
    int f4 = threadIdx.x % D4;
    int grp = threadIdx.x / D4;
    int chunk = n_per / 8;
    int base = g * n_per + ch * chunk;
    const float4* x4 = reinterpret_cast<const float4*>(x);
    float4 s1 = {0.f, 0.f, 0.f, 0.f}, s2 = {0.f, 0.f, 0.f, 0.f};
    for (int i = grp; i < chunk; i += GROUPS) {
        float4 v = x4[(size_t)(base + i) * D4 + f4];
        s1.x += v.x; s1.y += v.y; s1.z += v.z; s1.w += v.w;
        s2.x += v.x * v.x; s2.y += v.y * v.y; s2.z += v.z * v.z; s2.w += v.w * v.w;
    }
    int t = threadIdx.x;
    l1[t] = s1; l2[t] = s2;
    __syncthreads();
    for (int str = 128; str >= D4; str >>= 1) {
        if (t < str) {
            float4 a = l1[t + str], b2 = l2[t + str];
            l1[t].x += a.x; l1[t].y += a.y; l1[t].z += a.z; l1[t].w += a.w;
            l2[t].x += b2.x; l2[t].y += b2.y; l2[t].z += b2.z; l2[t].w += b2.w;
        }
        __syncthreads();
    }
    if (t < D4) {
        float4 a = l1[t], b2 = l2[t];
        float* p1 = sum1 + g * (D4 * 4) + t * 4;
        float* p2 = sum2 + g * (D4 * 4) + t * 4;
        unsafeAtomicAdd(p1 + 0, a.x); unsafeAtomicAdd(p1 + 1, a.y);
        unsafeAtomicAdd(p1 + 2, a.z); unsafeAtomicAdd(p1 + 3, a.w);
        unsafeAtomicAdd(p2 + 0, b2.x); unsafeAtomicAdd(p2 + 1, b2.y);
        unsafeAtomicAdd(p2 + 2, b2.z); unsafeAtomicAdd(p2 + 3, b2.w);
    }
}

__global__ void gn_final_kernel(const float* __restrict__ sum1, const float* __restrict__ sum2,
                                const float* __restrict__ ms, const float* __restrict__ w,
                                float* __restrict__ cmean, float* __restrict__ srw,
                                int n_per, int D, int total) {
    int t = blockIdx.x * blockDim.x + threadIdx.x;
    if (t >= total) return;
    int f = t % D;
    float inv_n = 1.0f / (float)n_per;
    float mean = sum1[t] * inv_n;
    float ex2  = sum2[t] * inv_n;
    float m = ms[f];
    float var = ex2 - 2.f * m * mean * mean + m * m * mean * mean;
    cmean[t] = m * mean;
    srw[t]   = w[f] * rsqrtf(var + GN_EPS);
}

// ---------------------------------------------------------------- 1/||p||
__global__ void pnorm_kernel(const float* __restrict__ p, float* __restrict__ out, int do_) {
    __shared__ float red[256];
    int t = threadIdx.x;
    float v = (t < do_) ? p[t] : 0.0f;
    red[t] = v * v;
    __syncthreads();
    for (int s = 128; s; s >>= 1) {
        if (t < s) red[t] += red[t + s];
        __syncthreads();
    }
    if (t == 0) out[0] = 1.0f / sqrtf(red[0]);
}

// ---------------------------------------------------------------- graphnorm apply + relu + score
template <int DO>
__global__ __launch_bounds__(256) void gn_apply_score_kernel(
        float* __restrict__ x, const float* __restrict__ cmean, const float* __restrict__ srw,
        const float* __restrict__ bias, const float* __restrict__ p,
        const float* __restrict__ pinv, float* __restrict__ score, int n_per) {
    constexpr int V = DO / 64;
    int node = blockIdx.x * 4 + (threadIdx.x >> 6);
    int lane = threadIdx.x & 63;
    int g = node / n_per;
    float*       xr = x + (size_t)node * DO + lane * V;
    const float* cm = cmean + g * DO + lane * V;
    const float* sw = srw + g * DO + lane * V;
    const float* bb = bias + lane * V;
    const float* pp = p + lane * V;
    float dot = 0.f;
#pragma unroll
    for (int i = 0; i < V; i++) {
        float y = (xr[i] - cm[i]) * sw[i] + bb[i];
        y = fmaxf(y, 0.0f);
        xr[i] = y;
        dot += y * pp[i];
    }
#pragma unroll
    for (int off = 32; off; off >>= 1) dot += __shfl_xor(dot, off);
    if (lane == 0) score[node] = tanhf(dot * pinv[0]);
}

// ---------------------------------------------------------------- top-k (rank based, lax.top_k tie-break)
__global__ void topk_kernel(const float* __restrict__ score, int* __restrict__ mapping,
                            int* __restrict__ inv, int n_per, int k) {
    __shared__ float s[1024];
    int g = blockIdx.x;
    int i = threadIdx.x;             // blockDim == n_per
    float si = score[g * n_per + i];
    s[i] = si;
    __syncthreads();
    int rank = 0;
    for (int j = 0; j < n_per; j++) {
        float sj = s[j];
        rank += (sj > si) || (sj == si && j < i);
    }
    int old_g = g * n_per + i;
    if (rank < k) {
        int neu = g * k + rank;
        mapping[old_g] = neu;
        inv[neu] = old_g;
    } else {
        mapping[old_g] = -1;
    }
}

// ---------------------------------------------------------------- permute + scale by score
__global__ void permute_scale_kernel(const float* __restrict__ x, const int* __restrict__ inv,
                                     const float* __restrict__ score, float* __restrict__ xn,
                                     int total, int ldof4) {
    int t = blockIdx.x * blockDim.x + threadIdx.x;
    if (t >= total) return;
    int node = t >> ldof4;
    int f4   = t & ((1 << ldof4) - 1);
    int dof4 = 1 << ldof4;
    int old = inv[node];
    float sc = score[old];
    float4 v = reinterpret_cast<const float4*>(x)[(size_t)old * dof4 + f4];
    float4 o = {v.x * sc, v.y * sc, v.z * sc, v.w * sc};
    reinterpret_cast<float4*>(xn)[t] = o;
}

// ---------------------------------------------------------------- edge remap
__global__ void remap_edges_kernel(int* __restrict__ esrc, int* __restrict__ edst,
                                   const int* __restrict__ mapping) {
    int e = blockIdx.x * blockDim.x + threadIdx.x;
    if (e >= ETOT) return;
    int s = esrc[e];
    if (s < 0) return;
    int ns = mapping[s];
    int nd = mapping[edst[e]];
    if (ns >= 0 && nd >= 0) { esrc[e] = ns; edst[e] = nd; }
    else                    { esrc[e] = -1; edst[e] = 0;  }
}

// ---------------------------------------------------------------- final mean/max pool
__global__ void pool_kernel(const float* __restrict__ x, float* __restrict__ out, int n_per) {
    int g = blockIdx.x;
    int f = threadIdx.x;             // 256 threads
    const float* xg = x + (size_t)g * n_per * 256;
    float s = 0.f, mx = -INFINITY;
    for (int i = 0; i < n_per; i++) {
        float v = xg[(size_t)i * 256 + f];
        s += v;
        mx = fmaxf(mx, v);
    }
    out[g * 512 + f]       = s / (float)n_per;
    out[g * 512 + 256 + f] = mx;
}

// ================================================================ host
static inline int cdiv_h(int a, int b) { return (a + b - 1) / b; }

extern "C" void kernel_launch(void* const* d_in, const int* in_sizes, int n_in,
                              void* d_out, int out_size, void* d_ws, size_t ws_size,
                              hipStream_t stream) {
    (void)in_sizes; (void)n_in; (void)out_size; (void)ws_size;

    const float* x_in = (const float*)d_in[0];
    const int*   ei   = (const int*)d_in[1];
    // d_in[2] = batch (unused, equal-sized graphs)
    const float* Wm[3]  = {(const float*)d_in[3],  (const float*)d_in[9],  (const float*)d_in[15]};
    const float* bv[3]  = {(const float*)d_in[4],  (const float*)d_in[10], (const float*)d_in[16]};
    const float* gnw[3] = {(const float*)d_in[5],  (const float*)d_in[11], (const float*)d_in[17]};
    const float* gnb[3] = {(const float*)d_in[6],  (const float*)d_in[12], (const float*)d_in[18]};
    const float* gnm[3] = {(const float*)d_in[7],  (const float*)d_in[13], (const float*)d_in[19]};
    const float* pv[3]  = {(const float*)d_in[8],  (const float*)d_in[14], (const float*)d_in[20]};

    // workspace carve
    size_t off = 0;
    auto alloc = [&](size_t bytes) {
        void* p = (char*)d_ws + off;
        off += (bytes + 255) & ~(size_t)255;
        return p;
    };
    float* X1      = (float*)alloc((size_t)65536 * 128 * 4);
    float* H       = (float*)alloc((size_t)65536 * 128 * 4);
    float* X2      = (float*)alloc((size_t)32768 * 128 * 4);
    int*   esrc    = (int*)alloc((size_t)ETOT * 4);
    int*   edst    = (int*)alloc((size_t)ETOT * 4);
    int*   csr_src = (int*)alloc((size_t)ETOT * 4);
    float* csr_nrm = (float*)alloc((size_t)ETOT * 4);
    int*   cnt     = (int*)alloc(65536 * 4);
    int*   offs    = (int*)alloc(65536 * 4);
    int*   fillpos = (int*)alloc(65536 * 4);
    int*   blksum  = (int*)alloc(256 * 4);
    float* score   = (float*)alloc(65536 * 4);
    int*   mapping = (int*)alloc(65536 * 4);
    int*   inv     = (int*)alloc(32768 * 4);
    float* sum1    = (float*)alloc(64 * 256 * 4);
    float* sum2    = (float*)alloc(64 * 256 * 4);
    float* cmean   = (float*)alloc(64 * 256 * 4);
    float* srw     = (float*)alloc(64 * 256 * 4);
    float* pinv    = (float*)alloc(256);

    const int nper[4] = {1024, 512, 256, 128};
    const int din[3]  = {100, 128, 128};
    const int dof[3]  = {128, 128, 256};

    edge_init_kernel<<<cdiv_h(ETOT, 256), 256, 0, stream>>>(ei, esrc, edst);

    for (int L = 0; L < 3; L++) {
        const int n    = NB * nper[L];
        const int k    = nper[L + 1];
        const int nn   = NB * k;
        const int D    = dof[L];
        const int dof4 = D / 4;
        const int ldof4 = (dof4 == 32) ? 5 : 6;
        const float* xin = (L == 0) ? x_in : X2;
        const int nblk = n / 256;

        // ---- in-degree counts + CSR build
        hipMemsetAsync(cnt, 0, n * sizeof(int), stream);
        deg_count_kernel<<<cdiv_h(ETOT, 256), 256, 0, stream>>>(esrc, edst, cnt);
        scan1_kernel<<<nblk, 256, 0, stream>>>(cnt, offs, blksum, n);
        scan2_kernel<<<1, 256, 0, stream>>>(blksum, nblk);
        scan3_kernel<<<nblk, 256, 0, stream>>>(offs, blksum, fillpos, n);
        csr_fill_kernel<<<cdiv_h(ETOT, 256), 256, 0, stream>>>(esrc, edst, cnt, fillpos,
                                                               csr_src, csr_nrm);

        // ---- h = x @ W
        gemm64_kernel<<<dim3(n / 64, D / 64), 256, 0, stream>>>(xin, Wm[L], H, n, D, din[L]);

        // ---- fused aggregate: X1 = gather + h/deg + b (graph-affine XCD swizzle)
        if (dof4 == 32) {
            const int NPB = 8;                   // nodes per block
            const int bpg = nper[L] / NPB;       // blocks per graph
            gather_kernel<32><<<n / NPB, 256, 0, stream>>>(H, cnt, offs, csr_src, csr_nrm,
                                                           bv[L], X1, n, bpg);
        } else {
            const int NPB = 4;
            const int bpg = nper[L] / NPB;
            gather_kernel<64><<<n / NPB, 256, 0, stream>>>(H, cnt, offs, csr_src, csr_nrm,
                                                           bv[L], X1, n, bpg);
        }

        // ---- graphnorm stats
        hipMemsetAsync(sum1, 0, NB * D * sizeof(float), stream);
        hipMemsetAsync(sum2, 0, NB * D * sizeof(float), stream);
        if (dof4 == 32)
            gn_partial_kernel<32><<<NB * 8, 256, 0, stream>>>(X1, sum1, sum2, nper[L]);
        else
            gn_partial_kernel<64><<<NB * 8, 256, 0, stream>>>(X1, sum1, sum2, nper[L]);
        gn_final_kernel<<<cdiv_h(NB * D, 256), 256, 0, stream>>>(sum1, sum2, gnm[L], gnw[L],
                                                                 cmean, srw, nper[L], D, NB * D);
        pnorm_kernel<<<1, 256, 0, stream>>>(pv[L], pinv, D);
        if (D == 128)
            gn_apply_score_kernel<128><<<n / 4, 256, 0, stream>>>(X1, cmean, srw, gnb[L],
                                                                  pv[L], pinv, score, nper[L]);
        else
            gn_apply_score_kernel<256><<<n / 4, 256, 0, stream>>>(X1, cmean, srw, gnb[L],
                                                                  pv[L], pinv, score, nper[L]);

        // ---- top-k pooling
        topk_kernel<<<NB, nper[L], 0, stream>>>(score, mapping, inv, nper[L], k);
        permute_scale_kernel<<<cdiv_h(nn * dof4, 256), 256, 0, stream>>>(X1, inv, score, X2,
                                                                         nn * dof4, ldof4);
        remap_edges_kernel<<<cdiv_h(ETOT, 256), 256, 0, stream>>>(esrc, edst, mapping);
    }

    // final mean/max pool -> [64, 512]
    pool_kernel<<<NB, 256, 0, stream>>>(X2, (float*)d_out, nper[3]);
}

// Round 7
// 468.005 us; speedup vs baseline: 7.0261x; 1.1113x over previous
//
#include <hip/hip_runtime.h>

#define GN_EPS 1e-5f

constexpr int NB   = 64;             // graphs
constexpr int ETOT = 64 * 1024 * 16; // 1048576 edges

// ---------------------------------------------------------------- edge init
__global__ void edge_init_kernel(const int* __restrict__ ei,
                                 int* __restrict__ esrc, int* __restrict__ edst) {
    int e = blockIdx.x * blockDim.x + threadIdx.x;
    if (e >= ETOT) return;
    esrc[e] = ei[e];
    edst[e] = ei[ETOT + e];
}

// ---------------------------------------------------------------- in-degree count (int)
__global__ void deg_count_kernel(const int* __restrict__ esrc, const int* __restrict__ edst,
                                 int* __restrict__ cnt) {
    int e = blockIdx.x * blockDim.x + threadIdx.x;
    if (e >= ETOT) return;
    int s = esrc[e];
    if (s < 0) return;
    atomicAdd(&cnt[edst[e]], 1);
}

// ---------------------------------------------------------------- 2-level exclusive scan
__global__ void scan1_kernel(const int* __restrict__ cnt, int* __restrict__ offs,
                             int* __restrict__ blksum, int n) {
    __shared__ int s[256];
    int t = threadIdx.x;
    int i = blockIdx.x * 256 + t;
    int v = (i < n) ? cnt[i] : 0;
    s[t] = v;
    __syncthreads();
    for (int d = 1; d < 256; d <<= 1) {
        int x = (t >= d) ? s[t - d] : 0;
        __syncthreads();
        s[t] += x;
        __syncthreads();
    }
    if (i < n) offs[i] = s[t] - v;              // exclusive
    if (t == 255) blksum[blockIdx.x] = s[255];
}

__global__ void scan2_kernel(int* __restrict__ blksum, int nb) {
    __shared__ int s[256];
    int t = threadIdx.x;
    int v = (t < nb) ? blksum[t] : 0;
    s[t] = v;
    __syncthreads();
    for (int d = 1; d < 256; d <<= 1) {
        int x = (t >= d) ? s[t - d] : 0;
        __syncthreads();
        s[t] += x;
        __syncthreads();
    }
    if (t < nb) blksum[t] = s[t] - v;           // exclusive over block sums
}

__global__ void scan3_kernel(int* __restrict__ offs, const int* __restrict__ blksum,
                             int* __restrict__ fillpos, int n) {
    int i = blockIdx.x * 256 + threadIdx.x;
    if (i >= n) return;
    int o = offs[i] + blksum[blockIdx.x];
    offs[i] = o;
    fillpos[i] = o;
}

// ---------------------------------------------------------------- CSR fill (src + precomputed norm)
__global__ void csr_fill_kernel(const int* __restrict__ esrc, const int* __restrict__ edst,
                                const int* __restrict__ cnt, int* __restrict__ fillpos,
                                int* __restrict__ csr_src, float* __restrict__ csr_norm) {
    int e = blockIdx.x * blockDim.x + threadIdx.x;
    if (e >= ETOT) return;
    int s = esrc[e];
    if (s < 0) return;
    int d = edst[e];
    int pos = atomicAdd(&fillpos[d], 1);
    csr_src[pos] = s;
    csr_norm[pos] = rsqrtf(1.0f + (float)cnt[s]) * rsqrtf(1.0f + (float)cnt[d]);
}

// ---------------------------------------------------------------- GEMM  C[M,N] = A[M,K] @ W[K,N]
// 128x128 tile, 256 threads, 8x8 per thread as 2x2 quadrants of 4x4.
// A staged transposed [k][m] (pad 132), B [k][n] (pad 132). Reads are
// broadcast (A) / 2-way (B) -> conflict-free. K-tail fully predicated
// (K%4==0 guarantees whole-float4 validity; fp32 rows stay 16B-aligned).
__global__ __launch_bounds__(256) void gemm128_kernel(const float* __restrict__ A,
                                                      const float* __restrict__ W,
                                                      float* __restrict__ C,
                                                      int M, int N, int K) {
    __shared__ float As[16][132];
    __shared__ float Bs[16][132];
    const int bm = blockIdx.x * 128;
    const int bn = blockIdx.y * 128;
    const int tid = threadIdx.x;
    const int tx = tid & 15, ty = tid >> 4;

    const int arow = tid >> 1;          // 0..127
    const int ak   = (tid & 1) * 8;     // 0 or 8
    const int brow = tid >> 5;          // 0..7
    const int bc4  = (tid & 31) * 4;    // 0..124

    float acc[2][2][4][4] = {};

    for (int k0 = 0; k0 < K; k0 += 16) {
        // ---- stage A (transpose to [k][m])
        {
            const float* ap = A + (size_t)(bm + arow) * K + k0 + ak;
            float4 a0 = {0,0,0,0}, a1 = {0,0,0,0};
            if (k0 + ak < K)     a0 = *reinterpret_cast<const float4*>(ap);
            if (k0 + ak + 4 < K) a1 = *reinterpret_cast<const float4*>(ap + 4);
            As[ak + 0][arow] = a0.x; As[ak + 1][arow] = a0.y;
            As[ak + 2][arow] = a0.z; As[ak + 3][arow] = a0.w;
            As[ak + 4][arow] = a1.x; As[ak + 5][arow] = a1.y;
            As[ak + 6][arow] = a1.z; As[ak + 7][arow] = a1.w;
        }
        // ---- stage B
        {
            float4 b0 = {0,0,0,0}, b1 = {0,0,0,0};
            if (k0 + brow < K)
                b0 = *reinterpret_cast<const float4*>(W + (size_t)(k0 + brow) * N + bn + bc4);
            if (k0 + brow + 8 < K)
                b1 = *reinterpret_cast<const float4*>(W + (size_t)(k0 + brow + 8) * N + bn + bc4);
            *reinterpret_cast<float4*>(&Bs[brow][bc4])     = b0;
            *reinterpret_cast<float4*>(&Bs[brow + 8][bc4]) = b1;
        }
        __syncthreads();
#pragma unroll
        for (int k = 0; k < 16; k++) {
            float4 a0 = *reinterpret_cast<const float4*>(&As[k][ty * 4]);
            float4 a1 = *reinterpret_cast<const float4*>(&As[k][64 + ty * 4]);
            float4 b0 = *reinterpret_cast<const float4*>(&Bs[k][tx * 4]);
            float4 b1 = *reinterpret_cast<const float4*>(&Bs[k][64 + tx * 4]);
            const float av[2][4] = {{a0.x, a0.y, a0.z, a0.w}, {a1.x, a1.y, a1.z, a1.w}};
            const float bv[2][4] = {{b0.x, b0.y, b0.z, b0.w}, {b1.x, b1.y, b1.z, b1.w}};
#pragma unroll
            for (int qi = 0; qi < 2; qi++)
#pragma unroll
                for (int qj = 0; qj < 2; qj++)
#pragma unroll
                    for (int i = 0; i < 4; i++)
#pragma unroll
                        for (int j = 0; j < 4; j++)
                            acc[qi][qj][i][j] += av[qi][i] * bv[qj][j];
        }
        __syncthreads();
    }
#pragma unroll
    for (int qi = 0; qi < 2; qi++)
#pragma unroll
        for (int i = 0; i < 4; i++) {
            int row = bm + qi * 64 + ty * 4 + i;
#pragma unroll
            for (int qj = 0; qj < 2; qj++) {
                float4 o = {acc[qi][qj][i][0], acc[qi][qj][i][1],
                            acc[qi][qj][i][2], acc[qi][qj][i][3]};
                *reinterpret_cast<float4*>(&C[(size_t)row * N + bn + qj * 64 + tx * 4]) = o;
            }
        }
}

// ---------------------------------------------------------------- CSR gather: out = sum h[src]*norm + h/deg + b
// XCD-affine swizzle: all blocks of one graph land on one XCD (L2 locality).
template <int D4>   // 32 (D=128) or 64 (D=256)
__global__ __launch_bounds__(256) void gather_kernel(
        const float* __restrict__ h, const int* __restrict__ cnt,
        const int* __restrict__ offs, const int* __restrict__ csr_src,
        const float* __restrict__ csr_norm, const float* __restrict__ b,
        float* __restrict__ out, int n, int bpg) {
    constexpr int NPB = 256 / D4;
    int bid   = blockIdx.x;
    int xcd   = bid & 7;
    int slot  = bid >> 3;
    int graph = xcd + 8 * (slot / bpg);
    int local = slot % bpg;
    int vb    = graph * bpg + local;

    int v  = vb * NPB + threadIdx.x / D4;
    int f4 = threadIdx.x % D4;
    if (v >= n) return;
    const float4* h4 = reinterpret_cast<const float4*>(h);
    int st = offs[v];
    int c  = cnt[v];
    float4 acc = {0.f, 0.f, 0.f, 0.f};
    int j = 0;
    for (; j + 4 <= c; j += 4) {
        int   s0 = csr_src[st + j],      s1 = csr_src[st + j + 1];
        int   s2 = csr_src[st + j + 2],  s3 = csr_src[st + j + 3];
        float n0 = csr_norm[st + j],     n1 = csr_norm[st + j + 1];
        float n2 = csr_norm[st + j + 2], n3 = csr_norm[st + j + 3];
        float4 h0 = h4[(size_t)s0 * D4 + f4];
        float4 h1 = h4[(size_t)s1 * D4 + f4];
        float4 h2 = h4[(size_t)s2 * D4 + f4];
        float4 h3 = h4[(size_t)s3 * D4 + f4];
        acc.x += h0.x * n0 + h1.x * n1 + h2.x * n2 + h3.x * n3;
        acc.y += h0.y * n0 + h1.y * n1 + h2.y * n2 + h3.y * n3;
        acc.z += h0.z * n0 + h1.z * n1 + h2.z * n2 + h3.z * n3;
        acc.w += h0.w * n0 + h1.w * n1 + h2.w * n2 + h3.w * n3;
    }
    for (; j < c; j++) {
        int s0 = csr_src[st + j];
        float n0 = csr_norm[st + j];
        float4 h0 = h4[(size_t)s0 * D4 + f4];
        acc.x += h0.x * n0; acc.y += h0.y * n0; acc.z += h0.z * n0; acc.w += h0.w * n0;
    }
    float invd = 1.0f / (1.0f + (float)c);
    float4 hv = h4[(size_t)v * D4 + f4];
    float4 bb = reinterpret_cast<const float4*>(b)[f4];
    float4 o;
    o.x = acc.x + hv.x * invd + bb.x;
    o.y = acc.y + hv.y * invd + bb.y;
    o.z = acc.z + hv.z * invd + bb.z;
    o.w = acc.w + hv.w * invd + bb.w;
    reinterpret_cast<float4*>(out)[(size_t)v * D4 + f4] = o;
}

// ---------------------------------------------------------------- graphnorm partial sums (slot writes, no atomics)
template <int D4>   // 32 or 64
__global__ __launch_bounds__(256) void gn_partial_kernel(
        const float* __restrict__ x, float* __restrict__ sum1, float* __restrict__ sum2,
        int n_per) {
    constexpr int GROUPS = 256 / D4;
    __shared__ float4 l1[256];
    __shared__ float4 l2[256];
    int g = blockIdx.x >> 3;          // graph
    int ch = blockIdx.x & 7;          // node chunk (8 chunks)
    int f4 = threadIdx.x % D4;
    int grp = threadIdx.x / D4;
    int chunk = n_per / 8;
    int base = g * n_per + ch * chunk;
    const float4* x4 = reinterpret_cast<const float4*>(x);
    float4 s1 = {0.f, 0.f, 0.f, 0.f}, s2 = {0.f, 0.f, 0.f, 0.f};
    for (int i = grp; i < chunk; i += GROUPS) {
        float4 v = x4[(size_t)(base + i) * D4 + f4];
        s1.x += v.x; s1.y += v.y; s1.z += v.z; s1.w += v.w;
        s2.x += v.x * v.x; s2.y += v.y * v.y; s2.z += v.z * v.z; s2.w += v.w * v.w;
    }
    int t = threadIdx.x;
    l1[t] = s1; l2[t] = s2;
    __syncthreads();
    for (int str = 128; str >= D4; str >>= 1) {
        if (t < str) {
            float4 a = l1[t + str], b2 = l2[t + str];
            l1[t].x += a.x; l1[t].y += a.y; l1[t].z += a.z; l1[t].w += a.w;
            l2[t].x += b2.x; l2[t].y += b2.y; l2[t].z += b2.z; l2[t].w += b2.w;
        }
        __syncthreads();
    }
    if (t < D4) {
        // slot layout: [(g*8 + ch) * D + t*4]
        size_t slot = (size_t)(g * 8 + ch) * (D4 * 4) + t * 4;
        *reinterpret_cast<float4*>(&sum1[slot]) = l1[t];
        *reinterpret_cast<float4*>(&sum2[slot]) = l2[t];
    }
}

__global__ void gn_final_kernel(const float* __restrict__ sum1, const float* __restrict__ sum2,
                                const float* __restrict__ ms, const float* __restrict__ w,
                                float* __restrict__ cmean, float* __restrict__ srw,
                                int n_per, int D, int total) {
    int t = blockIdx.x * blockDim.x + threadIdx.x;
    if (t >= total) return;
    int g = t / D;
    int f = t % D;
    float s1 = 0.f, s2 = 0.f;
    for (int ch = 0; ch < 8; ch++) {
        size_t slot = (size_t)(g * 8 + ch) * D + f;
        s1 += sum1[slot];
        s2 += sum2[slot];
    }
    float inv_n = 1.0f / (float)n_per;
    float mean = s1 * inv_n;
    float ex2  = s2 * inv_n;
    float m = ms[f];
    float var = ex2 - 2.f * m * mean * mean + m * m * mean * mean;
    cmean[t] = m * mean;
    srw[t]   = w[f] * rsqrtf(var + GN_EPS);
}

// ---------------------------------------------------------------- 1/||p|| for all 3 layers in one launch
__global__ void pnorm3_kernel(const float* __restrict__ p0, const float* __restrict__ p1,
                              const float* __restrict__ p2, int d0, int d1, int d2,
                              float* __restrict__ out) {
    __shared__ float red[256];
    const float* p = (blockIdx.x == 0) ? p0 : (blockIdx.x == 1) ? p1 : p2;
    int d          = (blockIdx.x == 0) ? d0 : (blockIdx.x == 1) ? d1 : d2;
    int t = threadIdx.x;
    float v = (t < d) ? p[t] : 0.0f;
    red[t] = v * v;
    __syncthreads();
    for (int s = 128; s; s >>= 1) {
        if (t < s) red[t] += red[t + s];
        __syncthreads();
    }
    if (t == 0) out[blockIdx.x] = 1.0f / sqrtf(red[0]);
}

// ---------------------------------------------------------------- graphnorm apply + relu + score
template <int DO>
__global__ __launch_bounds__(256) void gn_apply_score_kernel(
        float* __restrict__ x, const float* __restrict__ cmean, const float* __restrict__ srw,
        const float* __restrict__ bias, const float* __restrict__ p,
        const float* __restrict__ pinv, float* __restrict__ score, int n_per) {
    constexpr int V = DO / 64;
    int node = blockIdx.x * 4 + (threadIdx.x >> 6);
    int lane = threadIdx.x & 63;
    int g = node / n_per;
    float*       xr = x + (size_t)node * DO + lane * V;
    const float* cm = cmean + g * DO + lane * V;
    const float* sw = srw + g * DO + lane * V;
    const float* bb = bias + lane * V;
    const float* pp = p + lane * V;
    float dot = 0.f;
#pragma unroll
    for (int i = 0; i < V; i++) {
        float y = (xr[i] - cm[i]) * sw[i] + bb[i];
        y = fmaxf(y, 0.0f);
        xr[i] = y;
        dot += y * pp[i];
    }
#pragma unroll
    for (int off = 32; off; off >>= 1) dot += __shfl_xor(dot, off);
    if (lane == 0) score[node] = tanhf(dot * pinv[0]);
}

// ---------------------------------------------------------------- top-k (rank based, lax.top_k tie-break)
__global__ void topk_kernel(const float* __restrict__ score, int* __restrict__ mapping,
                            int* __restrict__ inv, int n_per, int k) {
    __shared__ float s[1024];
    int g = blockIdx.x;
    int i = threadIdx.x;             // blockDim == n_per
    float si = score[g * n_per + i];
    s[i] = si;
    __syncthreads();
    int rank = 0;
    for (int j = 0; j < n_per; j++) {
        float sj = s[j];
        rank += (sj > si) || (sj == si && j < i);
    }
    int old_g = g * n_per + i;
    if (rank < k) {
        int neu = g * k + rank;
        mapping[old_g] = neu;
        inv[neu] = old_g;
    } else {
        mapping[old_g] = -1;
    }
}

// ---------------------------------------------------------------- permute + scale by score
__global__ void permute_scale_kernel(const float* __restrict__ x, const int* __restrict__ inv,
                                     const float* __restrict__ score, float* __restrict__ xn,
                                     int total, int ldof4) {
    int t = blockIdx.x * blockDim.x + threadIdx.x;
    if (t >= total) return;
    int node = t >> ldof4;
    int f4   = t & ((1 << ldof4) - 1);
    int dof4 = 1 << ldof4;
    int old = inv[node];
    float sc = score[old];
    float4 v = reinterpret_cast<const float4*>(x)[(size_t)old * dof4 + f4];
    float4 o = {v.x * sc, v.y * sc, v.z * sc, v.w * sc};
    reinterpret_cast<float4*>(xn)[t] = o;
}

// ---------------------------------------------------------------- edge remap
__global__ void remap_edges_kernel(int* __restrict__ esrc, int* __restrict__ edst,
                                   const int* __restrict__ mapping) {
    int e = blockIdx.x * blockDim.x + threadIdx.x;
    if (e >= ETOT) return;
    int s = esrc[e];
    if (s < 0) return;
    int ns = mapping[s];
    int nd = mapping[edst[e]];
    if (ns >= 0 && nd >= 0) { esrc[e] = ns; edst[e] = nd; }
    else                    { esrc[e] = -1; edst[e] = 0;  }
}

// ---------------------------------------------------------------- final mean/max pool
__global__ void pool_kernel(const float* __restrict__ x, float* __restrict__ out, int n_per) {
    int g = blockIdx.x;
    int f = threadIdx.x;             // 256 threads
    const float* xg = x + (size_t)g * n_per * 256;
    float s = 0.f, mx = -INFINITY;
    for (int i = 0; i < n_per; i++) {
        float v = xg[(size_t)i * 256 + f];
        s += v;
        mx = fmaxf(mx, v);
    }
    out[g * 512 + f]       = s / (float)n_per;
    out[g * 512 + 256 + f] = mx;
}

// ================================================================ host
static inline int cdiv_h(int a, int b) { return (a + b - 1) / b; }

extern "C" void kernel_launch(void* const* d_in, const int* in_sizes, int n_in,
                              void* d_out, int out_size, void* d_ws, size_t ws_size,
                              hipStream_t stream) {
    (void)in_sizes; (void)n_in; (void)out_size; (void)ws_size;

    const float* x_in = (const float*)d_in[0];
    const int*   ei   = (const int*)d_in[1];
    // d_in[2] = batch (unused, equal-sized graphs)
    const float* Wm[3]  = {(const float*)d_in[3],  (const float*)d_in[9],  (const float*)d_in[15]};
    const float* bv[3]  = {(const float*)d_in[4],  (const float*)d_in[10], (const float*)d_in[16]};
    const float* gnw[3] = {(const float*)d_in[5],  (const float*)d_in[11], (const float*)d_in[17]};
    const float* gnb[3] = {(const float*)d_in[6],  (const float*)d_in[12], (const float*)d_in[18]};
    const float* gnm[3] = {(const float*)d_in[7],  (const float*)d_in[13], (const float*)d_in[19]};
    const float* pv[3]  = {(const float*)d_in[8],  (const float*)d_in[14], (const float*)d_in[20]};

    // workspace carve
    size_t off = 0;
    auto alloc = [&](size_t bytes) {
        void* p = (char*)d_ws + off;
        off += (bytes + 255) & ~(size_t)255;
        return p;
    };
    float* X1      = (float*)alloc((size_t)65536 * 128 * 4);
    float* H       = (float*)alloc((size_t)65536 * 128 * 4);
    float* X2      = (float*)alloc((size_t)32768 * 128 * 4);
    int*   esrc    = (int*)alloc((size_t)ETOT * 4);
    int*   edst    = (int*)alloc((size_t)ETOT * 4);
    int*   csr_src = (int*)alloc((size_t)ETOT * 4);
    float* csr_nrm = (float*)alloc((size_t)ETOT * 4);
    int*   cnt     = (int*)alloc(65536 * 4);
    int*   offs    = (int*)alloc(65536 * 4);
    int*   fillpos = (int*)alloc(65536 * 4);
    int*   blksum  = (int*)alloc(256 * 4);
    float* score   = (float*)alloc(65536 * 4);
    int*   mapping = (int*)alloc(65536 * 4);
    int*   inv     = (int*)alloc(32768 * 4);
    float* sum1    = (float*)alloc(64 * 8 * 256 * 4);   // per-chunk slots
    float* sum2    = (float*)alloc(64 * 8 * 256 * 4);
    float* cmean   = (float*)alloc(64 * 256 * 4);
    float* srw     = (float*)alloc(64 * 256 * 4);
    float* pinv    = (float*)alloc(256);

    const int nper[4] = {1024, 512, 256, 128};
    const int din[3]  = {100, 128, 128};
    const int dof[3]  = {128, 128, 256};

    edge_init_kernel<<<cdiv_h(ETOT, 256), 256, 0, stream>>>(ei, esrc, edst);
    pnorm3_kernel<<<3, 256, 0, stream>>>(pv[0], pv[1], pv[2], dof[0], dof[1], dof[2], pinv);

    for (int L = 0; L < 3; L++) {
        const int n    = NB * nper[L];
        const int k    = nper[L + 1];
        const int nn   = NB * k;
        const int D    = dof[L];
        const int dof4 = D / 4;
        const int ldof4 = (dof4 == 32) ? 5 : 6;
        const float* xin = (L == 0) ? x_in : X2;
        const int nblk = n / 256;

        // ---- in-degree counts + CSR build
        hipMemsetAsync(cnt, 0, n * sizeof(int), stream);
        deg_count_kernel<<<cdiv_h(ETOT, 256), 256, 0, stream>>>(esrc, edst, cnt);
        scan1_kernel<<<nblk, 256, 0, stream>>>(cnt, offs, blksum, n);
        scan2_kernel<<<1, 256, 0, stream>>>(blksum, nblk);
        scan3_kernel<<<nblk, 256, 0, stream>>>(offs, blksum, fillpos, n);
        csr_fill_kernel<<<cdiv_h(ETOT, 256), 256, 0, stream>>>(esrc, edst, cnt, fillpos,
                                                               csr_src, csr_nrm);

        // ---- h = x @ W  (128x128 tile GEMM)
        gemm128_kernel<<<dim3(n / 128, D / 128), 256, 0, stream>>>(xin, Wm[L], H, n, D, din[L]);

        // ---- fused aggregate: X1 = gather + h/deg + b (graph-affine XCD swizzle)
        if (dof4 == 32) {
            const int NPB = 8;                   // nodes per block
            const int bpg = nper[L] / NPB;       // blocks per graph
            gather_kernel<32><<<n / NPB, 256, 0, stream>>>(H, cnt, offs, csr_src, csr_nrm,
                                                           bv[L], X1, n, bpg);
        } else {
            const int NPB = 4;
            const int bpg = nper[L] / NPB;
            gather_kernel<64><<<n / NPB, 256, 0, stream>>>(H, cnt, offs, csr_src, csr_nrm,
                                                           bv[L], X1, n, bpg);
        }

        // ---- graphnorm stats (slot partials, no atomics/memset)
        if (dof4 == 32)
            gn_partial_kernel<32><<<NB * 8, 256, 0, stream>>>(X1, sum1, sum2, nper[L]);
        else
            gn_partial_kernel<64><<<NB * 8, 256, 0, stream>>>(X1, sum1, sum2, nper[L]);
        gn_final_kernel<<<cdiv_h(NB * D, 256), 256, 0, stream>>>(sum1, sum2, gnm[L], gnw[L],
                                                                 cmean, srw, nper[L], D, NB * D);
        if (D == 128)
            gn_apply_score_kernel<128><<<n / 4, 256, 0, stream>>>(X1, cmean, srw, gnb[L],
                                                                  pv[L], pinv + L, score, nper[L]);
        else
            gn_apply_score_kernel<256><<<n / 4, 256, 0, stream>>>(X1, cmean, srw, gnb[L],
                                                                  pv[L], pinv + L, score, nper[L]);

        // ---- top-k pooling
        topk_kernel<<<NB, nper[L], 0, stream>>>(score, mapping, inv, nper[L], k);
        permute_scale_kernel<<<cdiv_h(nn * dof4, 256), 256, 0, stream>>>(X1, inv, score, X2,
                                                                         nn * dof4, ldof4);
        remap_edges_kernel<<<cdiv_h(ETOT, 256), 256, 0, stream>>>(esrc, edst, mapping);
    }

    // final mean/max pool -> [64, 512]
    pool_kernel<<<NB, 256, 0, stream>>>(X2, (float*)d_out, nper[3]);
}

// Round 8
// 430.279 us; speedup vs baseline: 7.6422x; 1.0877x over previous
//
#include <hip/hip_runtime.h>

#define GN_EPS 1e-5f

constexpr int NB   = 64;             // graphs
constexpr int EPG  = 16384;          // edges per graph (static)
constexpr int ETOT = NB * EPG;       // 1048576 edges

// ---------------------------------------------------------------- fused per-graph CSR build
// One block per graph. Edges of graph g live at [g*EPG, (g+1)*EPG) forever
// (remap invalidates in place). Slack CSR layout: graph g's region starts at
// g*EPG. Replaces deg_count + 3-kernel scan + csr_fill with zero global atomics.
template <int NPG>   // nodes per graph this layer: 1024 / 512 / 256
__global__ __launch_bounds__(1024) void csr_build_kernel(
        const int* __restrict__ esrc, const int* __restrict__ edst,
        int* __restrict__ cnt, int* __restrict__ offs, float* __restrict__ dinv,
        int* __restrict__ csr_src) {
    __shared__ int lcnt[NPG];
    __shared__ int lscan[NPG];
    const int g = blockIdx.x;
    const int t = threadIdx.x;           // blockDim == NPG
    const int ebase = g * EPG;
    constexpr int EPT = EPG / NPG;

    lcnt[t] = 0;
    __syncthreads();
    // ---- count (LDS atomics)
#pragma unroll 4
    for (int i = 0; i < EPT; i++) {
        int e = ebase + t + i * NPG;     // coalesced
        int s = esrc[e];
        if (s >= 0) atomicAdd(&lcnt[edst[e] - g * NPG], 1);
    }
    __syncthreads();
    // ---- inclusive scan (Hillis-Steele)
    int v = lcnt[t];
    lscan[t] = v;
    __syncthreads();
    for (int d = 1; d < NPG; d <<= 1) {
        int x = (t >= d) ? lscan[t - d] : 0;
        __syncthreads();
        lscan[t] += x;
        __syncthreads();
    }
    int excl = lscan[t] - v;
    cnt[g * NPG + t]  = v;
    offs[g * NPG + t] = ebase + excl;            // slack base
    dinv[g * NPG + t] = rsqrtf(1.0f + (float)v);
    lcnt[t] = excl;                              // reuse as fill cursor
    __syncthreads();
    // ---- fill
#pragma unroll 4
    for (int i = 0; i < EPT; i++) {
        int e = ebase + t + i * NPG;
        int s = esrc[e];
        if (s >= 0) {
            int pos = atomicAdd(&lcnt[edst[e] - g * NPG], 1);
            csr_src[ebase + pos] = s;
        }
    }
}

// ---------------------------------------------------------------- GEMM  Hs[M,N] = (A[M,K] @ W[K,N]) * dinv[row]
// 128x128 tile, 256 threads, 8x8/thread as 2x2 quadrants of 4x4.
__global__ __launch_bounds__(256) void gemm128_kernel(const float* __restrict__ A,
                                                      const float* __restrict__ W,
                                                      const float* __restrict__ dinv,
                                                      float* __restrict__ C,
                                                      int M, int N, int K) {
    __shared__ float As[16][132];
    __shared__ float Bs[16][132];
    const int bm = blockIdx.x * 128;
    const int bn = blockIdx.y * 128;
    const int tid = threadIdx.x;
    const int tx = tid & 15, ty = tid >> 4;

    const int arow = tid >> 1;          // 0..127
    const int ak   = (tid & 1) * 8;     // 0 or 8
    const int brow = tid >> 5;          // 0..7
    const int bc4  = (tid & 31) * 4;    // 0..124

    float acc[2][2][4][4] = {};

    for (int k0 = 0; k0 < K; k0 += 16) {
        {   // stage A (transpose to [k][m])
            const float* ap = A + (size_t)(bm + arow) * K + k0 + ak;
            float4 a0 = {0,0,0,0}, a1 = {0,0,0,0};
            if (k0 + ak < K)     a0 = *reinterpret_cast<const float4*>(ap);
            if (k0 + ak + 4 < K) a1 = *reinterpret_cast<const float4*>(ap + 4);
            As[ak + 0][arow] = a0.x; As[ak + 1][arow] = a0.y;
            As[ak + 2][arow] = a0.z; As[ak + 3][arow] = a0.w;
            As[ak + 4][arow] = a1.x; As[ak + 5][arow] = a1.y;
            As[ak + 6][arow] = a1.z; As[ak + 7][arow] = a1.w;
        }
        {   // stage B
            float4 b0 = {0,0,0,0}, b1 = {0,0,0,0};
            if (k0 + brow < K)
                b0 = *reinterpret_cast<const float4*>(W + (size_t)(k0 + brow) * N + bn + bc4);
            if (k0 + brow + 8 < K)
                b1 = *reinterpret_cast<const float4*>(W + (size_t)(k0 + brow + 8) * N + bn + bc4);
            *reinterpret_cast<float4*>(&Bs[brow][bc4])     = b0;
            *reinterpret_cast<float4*>(&Bs[brow + 8][bc4]) = b1;
        }
        __syncthreads();
#pragma unroll
        for (int k = 0; k < 16; k++) {
            float4 a0 = *reinterpret_cast<const float4*>(&As[k][ty * 4]);
            float4 a1 = *reinterpret_cast<const float4*>(&As[k][64 + ty * 4]);
            float4 b0 = *reinterpret_cast<const float4*>(&Bs[k][tx * 4]);
            float4 b1 = *reinterpret_cast<const float4*>(&Bs[k][64 + tx * 4]);
            const float av[2][4] = {{a0.x, a0.y, a0.z, a0.w}, {a1.x, a1.y, a1.z, a1.w}};
            const float bv[2][4] = {{b0.x, b0.y, b0.z, b0.w}, {b1.x, b1.y, b1.z, b1.w}};
#pragma unroll
            for (int qi = 0; qi < 2; qi++)
#pragma unroll
                for (int qj = 0; qj < 2; qj++)
#pragma unroll
                    for (int i = 0; i < 4; i++)
#pragma unroll
                        for (int j = 0; j < 4; j++)
                            acc[qi][qj][i][j] += av[qi][i] * bv[qj][j];
        }
        __syncthreads();
    }
#pragma unroll
    for (int qi = 0; qi < 2; qi++)
#pragma unroll
        for (int i = 0; i < 4; i++) {
            int row = bm + qi * 64 + ty * 4 + i;
            float dv = dinv[row];
#pragma unroll
            for (int qj = 0; qj < 2; qj++) {
                float4 o = {acc[qi][qj][i][0] * dv, acc[qi][qj][i][1] * dv,
                            acc[qi][qj][i][2] * dv, acc[qi][qj][i][3] * dv};
                *reinterpret_cast<float4*>(&C[(size_t)row * N + bn + qj * 64 + tx * 4]) = o;
            }
        }
}

// ---------------------------------------------------------------- CSR gather
// out = dinv[v] * (Hs[v] + sum Hs[src]) + b     (Hs already row-scaled by dinv)
template <int D4>   // 32 (D=128) or 64 (D=256)
__global__ __launch_bounds__(256) void gather_kernel(
        const float* __restrict__ hs, const int* __restrict__ cnt,
        const int* __restrict__ offs, const float* __restrict__ dinv,
        const int* __restrict__ csr_src, const float* __restrict__ b,
        float* __restrict__ out, int n, int bpg) {
    constexpr int NPB = 256 / D4;
    int bid   = blockIdx.x;
    int xcd   = bid & 7;
    int slot  = bid >> 3;
    int graph = xcd + 8 * (slot / bpg);
    int local = slot % bpg;
    int vb    = graph * bpg + local;

    int v  = vb * NPB + threadIdx.x / D4;
    int f4 = threadIdx.x % D4;
    if (v >= n) return;
    const float4* h4 = reinterpret_cast<const float4*>(hs);
    int st = offs[v];
    int c  = cnt[v];
    float4 acc = h4[(size_t)v * D4 + f4];        // self term
    int j = 0;
    for (; j + 4 <= c; j += 4) {
        int s0 = csr_src[st + j],     s1 = csr_src[st + j + 1];
        int s2 = csr_src[st + j + 2], s3 = csr_src[st + j + 3];
        float4 h0 = h4[(size_t)s0 * D4 + f4];
        float4 h1 = h4[(size_t)s1 * D4 + f4];
        float4 h2 = h4[(size_t)s2 * D4 + f4];
        float4 h3 = h4[(size_t)s3 * D4 + f4];
        acc.x += h0.x + h1.x + h2.x + h3.x;
        acc.y += h0.y + h1.y + h2.y + h3.y;
        acc.z += h0.z + h1.z + h2.z + h3.z;
        acc.w += h0.w + h1.w + h2.w + h3.w;
    }
    for (; j < c; j++) {
        int s0 = csr_src[st + j];
        float4 h0 = h4[(size_t)s0 * D4 + f4];
        acc.x += h0.x; acc.y += h0.y; acc.z += h0.z; acc.w += h0.w;
    }
    float dv = dinv[v];
    float4 bb = reinterpret_cast<const float4*>(b)[f4];
    float4 o;
    o.x = acc.x * dv + bb.x;
    o.y = acc.y * dv + bb.y;
    o.z = acc.z * dv + bb.z;
    o.w = acc.w * dv + bb.w;
    reinterpret_cast<float4*>(out)[(size_t)v * D4 + f4] = o;
}

// ---------------------------------------------------------------- graphnorm partial sums (slot writes, no atomics)
template <int D4>   // 32 or 64
__global__ __launch_bounds__(256) void gn_partial_kernel(
        const float* __restrict__ x, float* __restrict__ sum1, float* __restrict__ sum2,
        int n_per) {
    constexpr int GROUPS = 256 / D4;
    __shared__ float4 l1[256];
    __shared__ float4 l2[256];
    int g = blockIdx.x >> 3;          // graph
    int ch = blockIdx.x & 7;          // node chunk (8 chunks)
    int f4 = threadIdx.x % D4;
    int grp = threadIdx.x / D4;
    int chunk = n_per / 8;
    int base = g * n_per + ch * chunk;
    const float4* x4 = reinterpret_cast<const float4*>(x);
    float4 s1 = {0.f, 0.f, 0.f, 0.f}, s2 = {0.f, 0.f, 0.f, 0.f};
    for (int i = grp; i < chunk; i += GROUPS) {
        float4 v = x4[(size_t)(base + i) * D4 + f4];
        s1.x += v.x; s1.y += v.y; s1.z += v.z; s1.w += v.w;
        s2.x += v.x * v.x; s2.y += v.y * v.y; s2.z += v.z * v.z; s2.w += v.w * v.w;
    }
    int t = threadIdx.x;
    l1[t] = s1; l2[t] = s2;
    __syncthreads();
    for (int str = 128; str >= D4; str >>= 1) {
        if (t < str) {
            float4 a = l1[t + str], b2 = l2[t + str];
            l1[t].x += a.x; l1[t].y += a.y; l1[t].z += a.z; l1[t].w += a.w;
            l2[t].x += b2.x; l2[t].y += b2.y; l2[t].z += b2.z; l2[t].w += b2.w;
        }
        __syncthreads();
    }
    if (t < D4) {
        size_t slot = (size_t)(g * 8 + ch) * (D4 * 4) + t * 4;
        *reinterpret_cast<float4*>(&sum1[slot]) = l1[t];
        *reinterpret_cast<float4*>(&sum2[slot]) = l2[t];
    }
}

__global__ void gn_final_kernel(const float* __restrict__ sum1, const float* __restrict__ sum2,
                                const float* __restrict__ ms, const float* __restrict__ w,
                                float* __restrict__ cmean, float* __restrict__ srw,
                                int n_per, int D, int total) {
    int t = blockIdx.x * blockDim.x + threadIdx.x;
    if (t >= total) return;
    int g = t / D;
    int f = t % D;
    float s1 = 0.f, s2 = 0.f;
    for (int ch = 0; ch < 8; ch++) {
        size_t slot = (size_t)(g * 8 + ch) * D + f;
        s1 += sum1[slot];
        s2 += sum2[slot];
    }
    float inv_n = 1.0f / (float)n_per;
    float mean = s1 * inv_n;
    float ex2  = s2 * inv_n;
    float m = ms[f];
    float var = ex2 - 2.f * m * mean * mean + m * m * mean * mean;
    cmean[t] = m * mean;
    srw[t]   = w[f] * rsqrtf(var + GN_EPS);
}

// ---------------------------------------------------------------- 1/||p|| for all 3 layers in one launch
__global__ void pnorm3_kernel(const float* __restrict__ p0, const float* __restrict__ p1,
                              const float* __restrict__ p2, int d0, int d1, int d2,
                              float* __restrict__ out) {
    __shared__ float red[256];
    const float* p = (blockIdx.x == 0) ? p0 : (blockIdx.x == 1) ? p1 : p2;
    int d          = (blockIdx.x == 0) ? d0 : (blockIdx.x == 1) ? d1 : d2;
    int t = threadIdx.x;
    float v = (t < d) ? p[t] : 0.0f;
    red[t] = v * v;
    __syncthreads();
    for (int s = 128; s; s >>= 1) {
        if (t < s) red[t] += red[t + s];
        __syncthreads();
    }
    if (t == 0) out[blockIdx.x] = 1.0f / sqrtf(red[0]);
}

// ---------------------------------------------------------------- graphnorm apply + relu + score
template <int DO>
__global__ __launch_bounds__(256) void gn_apply_score_kernel(
        float* __restrict__ x, const float* __restrict__ cmean, const float* __restrict__ srw,
        const float* __restrict__ bias, const float* __restrict__ p,
        const float* __restrict__ pinv, float* __restrict__ score, int n_per) {
    constexpr int V = DO / 64;
    int node = blockIdx.x * 4 + (threadIdx.x >> 6);
    int lane = threadIdx.x & 63;
    int g = node / n_per;
    float*       xr = x + (size_t)node * DO + lane * V;
    const float* cm = cmean + g * DO + lane * V;
    const float* sw = srw + g * DO + lane * V;
    const float* bb = bias + lane * V;
    const float* pp = p + lane * V;
    float dot = 0.f;
#pragma unroll
    for (int i = 0; i < V; i++) {
        float y = (xr[i] - cm[i]) * sw[i] + bb[i];
        y = fmaxf(y, 0.0f);
        xr[i] = y;
        dot += y * pp[i];
    }
#pragma unroll
    for (int off = 32; off; off >>= 1) dot += __shfl_xor(dot, off);
    if (lane == 0) score[node] = tanhf(dot * pinv[0]);
}

// ---------------------------------------------------------------- top-k (rank based, lax.top_k tie-break)
__global__ void topk_kernel(const float* __restrict__ score, int* __restrict__ mapping,
                            int* __restrict__ inv, int n_per, int k) {
    __shared__ float s[1024];
    int g = blockIdx.x;
    int i = threadIdx.x;             // blockDim == n_per
    float si = score[g * n_per + i];
    s[i] = si;
    __syncthreads();
    int rank = 0;
    for (int j = 0; j < n_per; j++) {
        float sj = s[j];
        rank += (sj > si) || (sj == si && j < i);
    }
    int old_g = g * n_per + i;
    if (rank < k) {
        int neu = g * k + rank;
        mapping[old_g] = neu;
        inv[neu] = old_g;
    } else {
        mapping[old_g] = -1;
    }
}

// ---------------------------------------------------------------- permute + scale by score
__global__ void permute_scale_kernel(const float* __restrict__ x, const int* __restrict__ inv,
                                     const float* __restrict__ score, float* __restrict__ xn,
                                     int total, int ldof4) {
    int t = blockIdx.x * blockDim.x + threadIdx.x;
    if (t >= total) return;
    int node = t >> ldof4;
    int f4   = t & ((1 << ldof4) - 1);
    int dof4 = 1 << ldof4;
    int old = inv[node];
    float sc = score[old];
    float4 v = reinterpret_cast<const float4*>(x)[(size_t)old * dof4 + f4];
    float4 o = {v.x * sc, v.y * sc, v.z * sc, v.w * sc};
    reinterpret_cast<float4*>(xn)[t] = o;
}

// ---------------------------------------------------------------- edge remap (separate in/out)
__global__ void remap_edges_kernel(const int* __restrict__ in_src, const int* __restrict__ in_dst,
                                   int* __restrict__ esrc, int* __restrict__ edst,
                                   const int* __restrict__ mapping) {
    int e = blockIdx.x * blockDim.x + threadIdx.x;
    if (e >= ETOT) return;
    int s = in_src[e];
    if (s < 0) { esrc[e] = -1; edst[e] = 0; return; }
    int ns = mapping[s];
    int nd = mapping[in_dst[e]];
    if (ns >= 0 && nd >= 0) { esrc[e] = ns; edst[e] = nd; }
    else                    { esrc[e] = -1; edst[e] = 0;  }
}

// ---------------------------------------------------------------- final mean/max pool
__global__ void pool_kernel(const float* __restrict__ x, float* __restrict__ out, int n_per) {
    int g = blockIdx.x;
    int f = threadIdx.x;             // 256 threads
    const float* xg = x + (size_t)g * n_per * 256;
    float s = 0.f, mx = -INFINITY;
    for (int i = 0; i < n_per; i++) {
        float v = xg[(size_t)i * 256 + f];
        s += v;
        mx = fmaxf(mx, v);
    }
    out[g * 512 + f]       = s / (float)n_per;
    out[g * 512 + 256 + f] = mx;
}

// ================================================================ host
static inline int cdiv_h(int a, int b) { return (a + b - 1) / b; }

extern "C" void kernel_launch(void* const* d_in, const int* in_sizes, int n_in,
                              void* d_out, int out_size, void* d_ws, size_t ws_size,
                              hipStream_t stream) {
    (void)in_sizes; (void)n_in; (void)out_size; (void)ws_size;

    const float* x_in = (const float*)d_in[0];
    const int*   ei   = (const int*)d_in[1];
    // d_in[2] = batch (unused, equal-sized graphs)
    const float* Wm[3]  = {(const float*)d_in[3],  (const float*)d_in[9],  (const float*)d_in[15]};
    const float* bv[3]  = {(const float*)d_in[4],  (const float*)d_in[10], (const float*)d_in[16]};
    const float* gnw[3] = {(const float*)d_in[5],  (const float*)d_in[11], (const float*)d_in[17]};
    const float* gnb[3] = {(const float*)d_in[6],  (const float*)d_in[12], (const float*)d_in[18]};
    const float* gnm[3] = {(const float*)d_in[7],  (const float*)d_in[13], (const float*)d_in[19]};
    const float* pv[3]  = {(const float*)d_in[8],  (const float*)d_in[14], (const float*)d_in[20]};

    // workspace carve
    size_t off = 0;
    auto alloc = [&](size_t bytes) {
        void* p = (char*)d_ws + off;
        off += (bytes + 255) & ~(size_t)255;
        return p;
    };
    float* X1      = (float*)alloc((size_t)65536 * 128 * 4);
    float* H       = (float*)alloc((size_t)65536 * 128 * 4);   // Hs (row-scaled)
    float* X2      = (float*)alloc((size_t)32768 * 128 * 4);
    int*   esrc    = (int*)alloc((size_t)ETOT * 4);
    int*   edst    = (int*)alloc((size_t)ETOT * 4);
    int*   csr_src = (int*)alloc((size_t)ETOT * 4);
    int*   cnt     = (int*)alloc(65536 * 4);
    int*   offs    = (int*)alloc(65536 * 4);
    float* dinv    = (float*)alloc(65536 * 4);
    float* score   = (float*)alloc(65536 * 4);
    int*   mapping = (int*)alloc(65536 * 4);
    int*   inv     = (int*)alloc(32768 * 4);
    float* sum1    = (float*)alloc(64 * 8 * 256 * 4);   // per-chunk slots
    float* sum2    = (float*)alloc(64 * 8 * 256 * 4);
    float* cmean   = (float*)alloc(64 * 256 * 4);
    float* srw     = (float*)alloc(64 * 256 * 4);
    float* pinv    = (float*)alloc(256);

    const int nper[4] = {1024, 512, 256, 128};
    const int din[3]  = {100, 128, 128};
    const int dof[3]  = {128, 128, 256};

    pnorm3_kernel<<<3, 256, 0, stream>>>(pv[0], pv[1], pv[2], dof[0], dof[1], dof[2], pinv);

    for (int L = 0; L < 3; L++) {
        const int n    = NB * nper[L];
        const int k    = nper[L + 1];
        const int nn   = NB * k;
        const int D    = dof[L];
        const int dof4 = D / 4;
        const int ldof4 = (dof4 == 32) ? 5 : 6;
        const float* xin = (L == 0) ? x_in : X2;
        const int* cur_src = (L == 0) ? ei : esrc;
        const int* cur_dst = (L == 0) ? ei + ETOT : edst;

        // ---- fused CSR build (counts + scan + fill + dinv), 1 block/graph
        if (nper[L] == 1024)
            csr_build_kernel<1024><<<NB, 1024, 0, stream>>>(cur_src, cur_dst, cnt, offs,
                                                            dinv, csr_src);
        else if (nper[L] == 512)
            csr_build_kernel<512><<<NB, 512, 0, stream>>>(cur_src, cur_dst, cnt, offs,
                                                          dinv, csr_src);
        else
            csr_build_kernel<256><<<NB, 256, 0, stream>>>(cur_src, cur_dst, cnt, offs,
                                                          dinv, csr_src);

        // ---- Hs = (x @ W) * dinv[row]
        gemm128_kernel<<<dim3(n / 128, D / 128), 256, 0, stream>>>(xin, Wm[L], dinv, H,
                                                                   n, D, din[L]);

        // ---- fused aggregate: X1 = dinv*(Hs[v] + sum Hs[src]) + b
        if (dof4 == 32) {
            const int NPB = 8;
            const int bpg = nper[L] / NPB;
            gather_kernel<32><<<n / NPB, 256, 0, stream>>>(H, cnt, offs, dinv, csr_src,
                                                           bv[L], X1, n, bpg);
        } else {
            const int NPB = 4;
            const int bpg = nper[L] / NPB;
            gather_kernel<64><<<n / NPB, 256, 0, stream>>>(H, cnt, offs, dinv, csr_src,
                                                           bv[L], X1, n, bpg);
        }

        // ---- graphnorm stats
        if (dof4 == 32)
            gn_partial_kernel<32><<<NB * 8, 256, 0, stream>>>(X1, sum1, sum2, nper[L]);
        else
            gn_partial_kernel<64><<<NB * 8, 256, 0, stream>>>(X1, sum1, sum2, nper[L]);
        gn_final_kernel<<<cdiv_h(NB * D, 256), 256, 0, stream>>>(sum1, sum2, gnm[L], gnw[L],
                                                                 cmean, srw, nper[L], D, NB * D);
        if (D == 128)
            gn_apply_score_kernel<128><<<n / 4, 256, 0, stream>>>(X1, cmean, srw, gnb[L],
                                                                  pv[L], pinv + L, score, nper[L]);
        else
            gn_apply_score_kernel<256><<<n / 4, 256, 0, stream>>>(X1, cmean, srw, gnb[L],
                                                                  pv[L], pinv + L, score, nper[L]);

        // ---- top-k pooling
        topk_kernel<<<NB, nper[L], 0, stream>>>(score, mapping, inv, nper[L], k);
        permute_scale_kernel<<<cdiv_h(nn * dof4, 256), 256, 0, stream>>>(X1, inv, score, X2,
                                                                         nn * dof4, ldof4);
        remap_edges_kernel<<<cdiv_h(ETOT, 256), 256, 0, stream>>>(cur_src, cur_dst,
                                                                  esrc, edst, mapping);
    }

    // final mean/max pool -> [64, 512]
    pool_kernel<<<NB, 256, 0, stream>>>(X2, (float*)d_out, nper[3]);
}

// Round 9
// 354.670 us; speedup vs baseline: 9.2713x; 1.2132x over previous
//
#include <hip/hip_runtime.h>

#define GN_EPS 1e-5f

constexpr int NB   = 64;             // graphs
constexpr int EPG  = 16384;          // edges per graph (static)
constexpr int ETOT = NB * EPG;       // 1048576 edges
constexpr int NTOT = 64 * 1024;      // original nodes

// ---------------------------------------------------------------- cmap init (identity)
__global__ void cmap_init_kernel(int* __restrict__ cmap) {
    int i = blockIdx.x * blockDim.x + threadIdx.x;
    if (i < NTOT) cmap[i] = i;
}

// ---------------------------------------------------------------- compose mapping: cmap = mapping o cmap
__global__ void compose_map_kernel(int* __restrict__ cmap, const int* __restrict__ mapping) {
    int i = blockIdx.x * blockDim.x + threadIdx.x;
    if (i >= NTOT) return;
    int c = cmap[i];
    cmap[i] = (c >= 0) ? mapping[c] : -1;
}

// ---------------------------------------------------------------- fused per-graph CSR build
// One 1024-thread block per graph; reads ORIGINAL edges + composed cmap.
// Counts (LDS atomics) -> LDS scan -> fill, endpoints cached in registers.
// Slack layout: graph g's CSR region starts at g*EPG.
template <int NPG>   // nodes per graph this layer: 1024 / 512 / 256
__global__ __launch_bounds__(1024) void csr_build_kernel(
        const int* __restrict__ ei, const int* __restrict__ cmap,
        int* __restrict__ cnt, int* __restrict__ offs, float* __restrict__ dinv,
        int* __restrict__ csr_src) {
    __shared__ int lcnt[NPG];
    __shared__ int lscan[NPG];
    const int g = blockIdx.x;
    const int t = threadIdx.x;           // 1024 threads
    const int ebase = g * EPG;
    constexpr int EPT = EPG / 1024;      // 16

    for (int i = t; i < NPG; i += 1024) lcnt[i] = 0;
    __syncthreads();

    int ms_[EPT], md_[EPT];
#pragma unroll
    for (int i = 0; i < EPT; i++) {
        int e = ebase + t + i * 1024;                // coalesced
        int s = cmap[ei[e]];
        int d = cmap[ei[ETOT + e]];
        bool ok = (s >= 0) && (d >= 0);
        ms_[i] = ok ? s : -1;
        md_[i] = ok ? (d - g * NPG) : 0;
        if (ok) atomicAdd(&lcnt[d - g * NPG], 1);
    }
    __syncthreads();

    // exclusive scan over NPG entries (first NPG threads)
    if (t < NPG) lscan[t] = lcnt[t];
    __syncthreads();
    for (int d = 1; d < NPG; d <<= 1) {
        int x = 0;
        if (t < NPG && t >= d) x = lscan[t - d];
        __syncthreads();
        if (t < NPG) lscan[t] += x;
        __syncthreads();
    }
    if (t < NPG) {
        int v = lcnt[t];
        int excl = lscan[t] - v;
        cnt[g * NPG + t]  = v;
        offs[g * NPG + t] = ebase + excl;
        dinv[g * NPG + t] = rsqrtf(1.0f + (float)v);
        lcnt[t] = excl;                              // fill cursor
    }
    __syncthreads();

#pragma unroll
    for (int i = 0; i < EPT; i++) {
        if (ms_[i] >= 0) {
            int pos = atomicAdd(&lcnt[md_[i]], 1);
            csr_src[ebase + pos] = ms_[i];
        }
    }
}

// ---------------------------------------------------------------- GEMM  Hs[M,N] = (A[M,K] @ W[K,N]) * dinv[row]
__global__ __launch_bounds__(256) void gemm128_kernel(const float* __restrict__ A,
                                                      const float* __restrict__ W,
                                                      const float* __restrict__ dinv,
                                                      float* __restrict__ C,
                                                      int M, int N, int K) {
    __shared__ float As[16][132];
    __shared__ float Bs[16][132];
    const int bm = blockIdx.x * 128;
    const int bn = blockIdx.y * 128;
    const int tid = threadIdx.x;
    const int tx = tid & 15, ty = tid >> 4;

    const int arow = tid >> 1;          // 0..127
    const int ak   = (tid & 1) * 8;     // 0 or 8
    const int brow = tid >> 5;          // 0..7
    const int bc4  = (tid & 31) * 4;    // 0..124

    float acc[2][2][4][4] = {};

    for (int k0 = 0; k0 < K; k0 += 16) {
        {   // stage A (transpose to [k][m])
            const float* ap = A + (size_t)(bm + arow) * K + k0 + ak;
            float4 a0 = {0,0,0,0}, a1 = {0,0,0,0};
            if (k0 + ak < K)     a0 = *reinterpret_cast<const float4*>(ap);
            if (k0 + ak + 4 < K) a1 = *reinterpret_cast<const float4*>(ap + 4);
            As[ak + 0][arow] = a0.x; As[ak + 1][arow] = a0.y;
            As[ak + 2][arow] = a0.z; As[ak + 3][arow] = a0.w;
            As[ak + 4][arow] = a1.x; As[ak + 5][arow] = a1.y;
            As[ak + 6][arow] = a1.z; As[ak + 7][arow] = a1.w;
        }
        {   // stage B
            float4 b0 = {0,0,0,0}, b1 = {0,0,0,0};
            if (k0 + brow < K)
                b0 = *reinterpret_cast<const float4*>(W + (size_t)(k0 + brow) * N + bn + bc4);
            if (k0 + brow + 8 < K)
                b1 = *reinterpret_cast<const float4*>(W + (size_t)(k0 + brow + 8) * N + bn + bc4);
            *reinterpret_cast<float4*>(&Bs[brow][bc4])     = b0;
            *reinterpret_cast<float4*>(&Bs[brow + 8][bc4]) = b1;
        }
        __syncthreads();
#pragma unroll
        for (int k = 0; k < 16; k++) {
            float4 a0 = *reinterpret_cast<const float4*>(&As[k][ty * 4]);
            float4 a1 = *reinterpret_cast<const float4*>(&As[k][64 + ty * 4]);
            float4 b0 = *reinterpret_cast<const float4*>(&Bs[k][tx * 4]);
            float4 b1 = *reinterpret_cast<const float4*>(&Bs[k][64 + tx * 4]);
            const float av[2][4] = {{a0.x, a0.y, a0.z, a0.w}, {a1.x, a1.y, a1.z, a1.w}};
            const float bv[2][4] = {{b0.x, b0.y, b0.z, b0.w}, {b1.x, b1.y, b1.z, b1.w}};
#pragma unroll
            for (int qi = 0; qi < 2; qi++)
#pragma unroll
                for (int qj = 0; qj < 2; qj++)
#pragma unroll
                    for (int i = 0; i < 4; i++)
#pragma unroll
                        for (int j = 0; j < 4; j++)
                            acc[qi][qj][i][j] += av[qi][i] * bv[qj][j];
        }
        __syncthreads();
    }
#pragma unroll
    for (int qi = 0; qi < 2; qi++)
#pragma unroll
        for (int i = 0; i < 4; i++) {
            int row = bm + qi * 64 + ty * 4 + i;
            float dv = dinv[row];
#pragma unroll
            for (int qj = 0; qj < 2; qj++) {
                float4 o = {acc[qi][qj][i][0] * dv, acc[qi][qj][i][1] * dv,
                            acc[qi][qj][i][2] * dv, acc[qi][qj][i][3] * dv};
                *reinterpret_cast<float4*>(&C[(size_t)row * N + bn + qj * 64 + tx * 4]) = o;
            }
        }
}

// ---------------------------------------------------------------- CSR gather
// out = dinv[v] * (Hs[v] + sum Hs[src]) + b     (Hs already row-scaled)
template <int D4>   // 32 (D=128) or 64 (D=256)
__global__ __launch_bounds__(256) void gather_kernel(
        const float* __restrict__ hs, const int* __restrict__ cnt,
        const int* __restrict__ offs, const float* __restrict__ dinv,
        const int* __restrict__ csr_src, const float* __restrict__ b,
        float* __restrict__ out, int n, int bpg) {
    constexpr int NPB = 256 / D4;
    int bid   = blockIdx.x;
    int xcd   = bid & 7;
    int slot  = bid >> 3;
    int graph = xcd + 8 * (slot / bpg);
    int local = slot % bpg;
    int vb    = graph * bpg + local;

    int v  = vb * NPB + threadIdx.x / D4;
    int f4 = threadIdx.x % D4;
    if (v >= n) return;
    const float4* h4 = reinterpret_cast<const float4*>(hs);
    int st = offs[v];
    int c  = cnt[v];
    float4 acc = h4[(size_t)v * D4 + f4];        // self term
    int j = 0;
    for (; j + 4 <= c; j += 4) {
        int s0 = csr_src[st + j],     s1 = csr_src[st + j + 1];
        int s2 = csr_src[st + j + 2], s3 = csr_src[st + j + 3];
        float4 h0 = h4[(size_t)s0 * D4 + f4];
        float4 h1 = h4[(size_t)s1 * D4 + f4];
        float4 h2 = h4[(size_t)s2 * D4 + f4];
        float4 h3 = h4[(size_t)s3 * D4 + f4];
        acc.x += h0.x + h1.x + h2.x + h3.x;
        acc.y += h0.y + h1.y + h2.y + h3.y;
        acc.z += h0.z + h1.z + h2.z + h3.z;
        acc.w += h0.w + h1.w + h2.w + h3.w;
    }
    for (; j < c; j++) {
        int s0 = csr_src[st + j];
        float4 h0 = h4[(size_t)s0 * D4 + f4];
        acc.x += h0.x; acc.y += h0.y; acc.z += h0.z; acc.w += h0.w;
    }
    float dv = dinv[v];
    float4 bb = reinterpret_cast<const float4*>(b)[f4];
    float4 o;
    o.x = acc.x * dv + bb.x;
    o.y = acc.y * dv + bb.y;
    o.z = acc.z * dv + bb.z;
    o.w = acc.w * dv + bb.w;
    reinterpret_cast<float4*>(out)[(size_t)v * D4 + f4] = o;
}

// ---------------------------------------------------------------- graphnorm partial sums (slot writes, no atomics)
template <int D4>   // 32 or 64
__global__ __launch_bounds__(256) void gn_partial_kernel(
        const float* __restrict__ x, float* __restrict__ sum1, float* __restrict__ sum2,
        int n_per) {
    constexpr int GROUPS = 256 / D4;
    __shared__ float4 l1[256];
    __shared__ float4 l2[256];
    int g = blockIdx.x >> 3;          // graph
    int ch = blockIdx.x & 7;          // node chunk (8 chunks)
    int f4 = threadIdx.x % D4;
    int grp = threadIdx.x / D4;
    int chunk = n_per / 8;
    int base = g * n_per + ch * chunk;
    const float4* x4 = reinterpret_cast<const float4*>(x);
    float4 s1 = {0.f, 0.f, 0.f, 0.f}, s2 = {0.f, 0.f, 0.f, 0.f};
    for (int i = grp; i < chunk; i += GROUPS) {
        float4 v = x4[(size_t)(base + i) * D4 + f4];
        s1.x += v.x; s1.y += v.y; s1.z += v.z; s1.w += v.w;
        s2.x += v.x * v.x; s2.y += v.y * v.y; s2.z += v.z * v.z; s2.w += v.w * v.w;
    }
    int t = threadIdx.x;
    l1[t] = s1; l2[t] = s2;
    __syncthreads();
    for (int str = 128; str >= D4; str >>= 1) {
        if (t < str) {
            float4 a = l1[t + str], b2 = l2[t + str];
            l1[t].x += a.x; l1[t].y += a.y; l1[t].z += a.z; l1[t].w += a.w;
            l2[t].x += b2.x; l2[t].y += b2.y; l2[t].z += b2.z; l2[t].w += b2.w;
        }
        __syncthreads();
    }
    if (t < D4) {
        size_t slot = (size_t)(g * 8 + ch) * (D4 * 4) + t * 4;
        *reinterpret_cast<float4*>(&sum1[slot]) = l1[t];
        *reinterpret_cast<float4*>(&sum2[slot]) = l2[t];
    }
}

__global__ void gn_final_kernel(const float* __restrict__ sum1, const float* __restrict__ sum2,
                                const float* __restrict__ ms, const float* __restrict__ w,
                                float* __restrict__ cmean, float* __restrict__ srw,
                                int n_per, int D, int total) {
    int t = blockIdx.x * blockDim.x + threadIdx.x;
    if (t >= total) return;
    int g = t / D;
    int f = t % D;
    float s1 = 0.f, s2 = 0.f;
    for (int ch = 0; ch < 8; ch++) {
        size_t slot = (size_t)(g * 8 + ch) * D + f;
        s1 += sum1[slot];
        s2 += sum2[slot];
    }
    float inv_n = 1.0f / (float)n_per;
    float mean = s1 * inv_n;
    float ex2  = s2 * inv_n;
    float m = ms[f];
    float var = ex2 - 2.f * m * mean * mean + m * m * mean * mean;
    cmean[t] = m * mean;
    srw[t]   = w[f] * rsqrtf(var + GN_EPS);
}

// ---------------------------------------------------------------- 1/||p|| for all 3 layers in one launch
__global__ void pnorm3_kernel(const float* __restrict__ p0, const float* __restrict__ p1,
                              const float* __restrict__ p2, int d0, int d1, int d2,
                              float* __restrict__ out) {
    __shared__ float red[256];
    const float* p = (blockIdx.x == 0) ? p0 : (blockIdx.x == 1) ? p1 : p2;
    int d          = (blockIdx.x == 0) ? d0 : (blockIdx.x == 1) ? d1 : d2;
    int t = threadIdx.x;
    float v = (t < d) ? p[t] : 0.0f;
    red[t] = v * v;
    __syncthreads();
    for (int s = 128; s; s >>= 1) {
        if (t < s) red[t] += red[t + s];
        __syncthreads();
    }
    if (t == 0) out[blockIdx.x] = 1.0f / sqrtf(red[0]);
}

// ---------------------------------------------------------------- graphnorm apply + relu + score
template <int DO>
__global__ __launch_bounds__(256) void gn_apply_score_kernel(
        float* __restrict__ x, const float* __restrict__ cmean, const float* __restrict__ srw,
        const float* __restrict__ bias, const float* __restrict__ p,
        const float* __restrict__ pinv, float* __restrict__ score, int n_per) {
    constexpr int V = DO / 64;
    int node = blockIdx.x * 4 + (threadIdx.x >> 6);
    int lane = threadIdx.x & 63;
    int g = node / n_per;
    float*       xr = x + (size_t)node * DO + lane * V;
    const float* cm = cmean + g * DO + lane * V;
    const float* sw = srw + g * DO + lane * V;
    const float* bb = bias + lane * V;
    const float* pp = p + lane * V;
    float dot = 0.f;
#pragma unroll
    for (int i = 0; i < V; i++) {
        float y = (xr[i] - cm[i]) * sw[i] + bb[i];
        y = fmaxf(y, 0.0f);
        xr[i] = y;
        dot += y * pp[i];
    }
#pragma unroll
    for (int off = 32; off; off >>= 1) dot += __shfl_xor(dot, off);
    if (lane == 0) score[node] = tanhf(dot * pinv[0]);
}

// ---------------------------------------------------------------- top-k (rank based, lax.top_k tie-break)
__global__ void topk_kernel(const float* __restrict__ score, int* __restrict__ mapping,
                            int* __restrict__ inv, int n_per, int k) {
    __shared__ float s[1024];
    int g = blockIdx.x;
    int i = threadIdx.x;             // blockDim == n_per
    float si = score[g * n_per + i];
    s[i] = si;
    __syncthreads();
    int rank = 0;
    for (int j = 0; j < n_per; j++) {
        float sj = s[j];
        rank += (sj > si) || (sj == si && j < i);
    }
    int old_g = g * n_per + i;
    if (rank < k) {
        int neu = g * k + rank;
        mapping[old_g] = neu;
        inv[neu] = old_g;
    } else {
        mapping[old_g] = -1;
    }
}

// ---------------------------------------------------------------- permute + scale by score
__global__ void permute_scale_kernel(const float* __restrict__ x, const int* __restrict__ inv,
                                     const float* __restrict__ score, float* __restrict__ xn,
                                     int total, int ldof4) {
    int t = blockIdx.x * blockDim.x + threadIdx.x;
    if (t >= total) return;
    int node = t >> ldof4;
    int f4   = t & ((1 << ldof4) - 1);
    int dof4 = 1 << ldof4;
    int old = inv[node];
    float sc = score[old];
    float4 v = reinterpret_cast<const float4*>(x)[(size_t)old * dof4 + f4];
    float4 o = {v.x * sc, v.y * sc, v.z * sc, v.w * sc};
    reinterpret_cast<float4*>(xn)[t] = o;
}

// ---------------------------------------------------------------- final mean/max pool (1024 thr, 4-chunk)
__global__ __launch_bounds__(1024) void pool_kernel(const float* __restrict__ x,
                                                    float* __restrict__ out, int n_per) {
    __shared__ float ssum[1024];
    __shared__ float smax[1024];
    int g = blockIdx.x;
    int f = threadIdx.x & 255;
    int ch = threadIdx.x >> 8;       // 0..3
    const float* xg = x + (size_t)g * n_per * 256;
    float s = 0.f, mx = -INFINITY;
    for (int i = ch; i < n_per; i += 4) {
        float v = xg[(size_t)i * 256 + f];
        s += v;
        mx = fmaxf(mx, v);
    }
    ssum[threadIdx.x] = s;
    smax[threadIdx.x] = mx;
    __syncthreads();
    if (ch == 0) {
#pragma unroll
        for (int c = 1; c < 4; c++) {
            s  += ssum[f + c * 256];
            mx  = fmaxf(mx, smax[f + c * 256]);
        }
        out[g * 512 + f]       = s / (float)n_per;
        out[g * 512 + 256 + f] = mx;
    }
}

// ================================================================ host
static inline int cdiv_h(int a, int b) { return (a + b - 1) / b; }

extern "C" void kernel_launch(void* const* d_in, const int* in_sizes, int n_in,
                              void* d_out, int out_size, void* d_ws, size_t ws_size,
                              hipStream_t stream) {
    (void)in_sizes; (void)n_in; (void)out_size; (void)ws_size;

    const float* x_in = (const float*)d_in[0];
    const int*   ei   = (const int*)d_in[1];
    // d_in[2] = batch (unused, equal-sized graphs)
    const float* Wm[3]  = {(const float*)d_in[3],  (const float*)d_in[9],  (const float*)d_in[15]};
    const float* bv[3]  = {(const float*)d_in[4],  (const float*)d_in[10], (const float*)d_in[16]};
    const float* gnw[3] = {(const float*)d_in[5],  (const float*)d_in[11], (const float*)d_in[17]};
    const float* gnb[3] = {(const float*)d_in[6],  (const float*)d_in[12], (const float*)d_in[18]};
    const float* gnm[3] = {(const float*)d_in[7],  (const float*)d_in[13], (const float*)d_in[19]};
    const float* pv[3]  = {(const float*)d_in[8],  (const float*)d_in[14], (const float*)d_in[20]};

    // workspace carve
    size_t off = 0;
    auto alloc = [&](size_t bytes) {
        void* p = (char*)d_ws + off;
        off += (bytes + 255) & ~(size_t)255;
        return p;
    };
    float* X1      = (float*)alloc((size_t)65536 * 128 * 4);
    float* H       = (float*)alloc((size_t)65536 * 128 * 4);   // Hs (row-scaled)
    float* X2      = (float*)alloc((size_t)32768 * 128 * 4);
    int*   csr_src = (int*)alloc((size_t)ETOT * 4);
    int*   cmap    = (int*)alloc(NTOT * 4);
    int*   cnt     = (int*)alloc(65536 * 4);
    int*   offs    = (int*)alloc(65536 * 4);
    float* dinv    = (float*)alloc(65536 * 4);
    float* score   = (float*)alloc(65536 * 4);
    int*   mapping = (int*)alloc(65536 * 4);
    int*   inv     = (int*)alloc(32768 * 4);
    float* sum1    = (float*)alloc(64 * 8 * 256 * 4);   // per-chunk slots
    float* sum2    = (float*)alloc(64 * 8 * 256 * 4);
    float* cmean   = (float*)alloc(64 * 256 * 4);
    float* srw     = (float*)alloc(64 * 256 * 4);
    float* pinv    = (float*)alloc(256);

    const int nper[4] = {1024, 512, 256, 128};
    const int din[3]  = {100, 128, 128};
    const int dof[3]  = {128, 128, 256};

    cmap_init_kernel<<<NTOT / 256, 256, 0, stream>>>(cmap);
    pnorm3_kernel<<<3, 256, 0, stream>>>(pv[0], pv[1], pv[2], dof[0], dof[1], dof[2], pinv);

    for (int L = 0; L < 3; L++) {
        const int n    = NB * nper[L];
        const int k    = nper[L + 1];
        const int nn   = NB * k;
        const int D    = dof[L];
        const int dof4 = D / 4;
        const int ldof4 = (dof4 == 32) ? 5 : 6;
        const float* xin = (L == 0) ? x_in : X2;

        // ---- fused CSR build from original edges + cmap
        if (nper[L] == 1024)
            csr_build_kernel<1024><<<NB, 1024, 0, stream>>>(ei, cmap, cnt, offs, dinv, csr_src);
        else if (nper[L] == 512)
            csr_build_kernel<512><<<NB, 1024, 0, stream>>>(ei, cmap, cnt, offs, dinv, csr_src);
        else
            csr_build_kernel<256><<<NB, 1024, 0, stream>>>(ei, cmap, cnt, offs, dinv, csr_src);

        // ---- Hs = (x @ W) * dinv[row]
        gemm128_kernel<<<dim3(n / 128, D / 128), 256, 0, stream>>>(xin, Wm[L], dinv, H,
                                                                   n, D, din[L]);

        // ---- fused aggregate: X1 = dinv*(Hs[v] + sum Hs[src]) + b
        if (dof4 == 32) {
            const int NPB = 8;
            const int bpg = nper[L] / NPB;
            gather_kernel<32><<<n / NPB, 256, 0, stream>>>(H, cnt, offs, dinv, csr_src,
                                                           bv[L], X1, n, bpg);
        } else {
            const int NPB = 4;
            const int bpg = nper[L] / NPB;
            gather_kernel<64><<<n / NPB, 256, 0, stream>>>(H, cnt, offs, dinv, csr_src,
                                                           bv[L], X1, n, bpg);
        }

        // ---- graphnorm stats
        if (dof4 == 32)
            gn_partial_kernel<32><<<NB * 8, 256, 0, stream>>>(X1, sum1, sum2, nper[L]);
        else
            gn_partial_kernel<64><<<NB * 8, 256, 0, stream>>>(X1, sum1, sum2, nper[L]);
        gn_final_kernel<<<cdiv_h(NB * D, 256), 256, 0, stream>>>(sum1, sum2, gnm[L], gnw[L],
                                                                 cmean, srw, nper[L], D, NB * D);
        if (D == 128)
            gn_apply_score_kernel<128><<<n / 4, 256, 0, stream>>>(X1, cmean, srw, gnb[L],
                                                                  pv[L], pinv + L, score, nper[L]);
        else
            gn_apply_score_kernel<256><<<n / 4, 256, 0, stream>>>(X1, cmean, srw, gnb[L],
                                                                  pv[L], pinv + L, score, nper[L]);

        // ---- top-k pooling
        topk_kernel<<<NB, nper[L], 0, stream>>>(score, mapping, inv, nper[L], k);
        permute_scale_kernel<<<cdiv_h(nn * dof4, 256), 256, 0, stream>>>(X1, inv, score, X2,
                                                                         nn * dof4, ldof4);
        if (L < 2)
            compose_map_kernel<<<NTOT / 256, 256, 0, stream>>>(cmap, mapping);
    }

    // final mean/max pool -> [64, 512]
    pool_kernel<<<NB, 1024, 0, stream>>>(X2, (float*)d_out, nper[3]);
}

// Round 10
// 309.231 us; speedup vs baseline: 10.6337x; 1.1469x over previous
//
#include <hip/hip_runtime.h>

#define GN_EPS 1e-5f

constexpr int NB   = 64;             // graphs
constexpr int EPG  = 16384;          // edges per graph (static)
constexpr int ETOT = NB * EPG;       // 1048576 edges
constexpr int NTOT = 64 * 1024;      // original nodes

// ---------------------------------------------------------------- cmap init (identity)
__global__ void cmap_init_kernel(int* __restrict__ cmap) {
    int i = blockIdx.x * blockDim.x + threadIdx.x;
    if (i < NTOT) cmap[i] = i;
}

// ---------------------------------------------------------------- compose mapping: cmap = mapping o cmap
__global__ void compose_map_kernel(int* __restrict__ cmap, const int* __restrict__ mapping) {
    int i = blockIdx.x * blockDim.x + threadIdx.x;
    if (i >= NTOT) return;
    int c = cmap[i];
    cmap[i] = (c >= 0) ? mapping[c] : -1;
}

// ---------------------------------------------------------------- fused per-graph CSR build
template <int NPG>   // nodes per graph this layer: 1024 / 512 / 256
__global__ __launch_bounds__(1024) void csr_build_kernel(
        const int* __restrict__ ei, const int* __restrict__ cmap,
        int* __restrict__ cnt, int* __restrict__ offs, float* __restrict__ dinv,
        int* __restrict__ csr_src) {
    __shared__ int lcnt[NPG];
    __shared__ int lscan[NPG];
    const int g = blockIdx.x;
    const int t = threadIdx.x;           // 1024 threads
    const int ebase = g * EPG;
    constexpr int EPT = EPG / 1024;      // 16

    for (int i = t; i < NPG; i += 1024) lcnt[i] = 0;
    __syncthreads();

    int ms_[EPT], md_[EPT];
#pragma unroll
    for (int i = 0; i < EPT; i++) {
        int e = ebase + t + i * 1024;                // coalesced
        int s = cmap[ei[e]];
        int d = cmap[ei[ETOT + e]];
        bool ok = (s >= 0) && (d >= 0);
        ms_[i] = ok ? s : -1;
        md_[i] = ok ? (d - g * NPG) : 0;
        if (ok) atomicAdd(&lcnt[d - g * NPG], 1);
    }
    __syncthreads();

    if (t < NPG) lscan[t] = lcnt[t];
    __syncthreads();
    for (int d = 1; d < NPG; d <<= 1) {
        int x = 0;
        if (t < NPG && t >= d) x = lscan[t - d];
        __syncthreads();
        if (t < NPG) lscan[t] += x;
        __syncthreads();
    }
    if (t < NPG) {
        int v = lcnt[t];
        int excl = lscan[t] - v;
        cnt[g * NPG + t]  = v;
        offs[g * NPG + t] = ebase + excl;
        dinv[g * NPG + t] = rsqrtf(1.0f + (float)v);
        lcnt[t] = excl;                              // fill cursor
    }
    __syncthreads();

#pragma unroll
    for (int i = 0; i < EPT; i++) {
        if (ms_[i] >= 0) {
            int pos = atomicAdd(&lcnt[md_[i]], 1);
            csr_src[ebase + pos] = ms_[i];
        }
    }
}

// ---------------------------------------------------------------- GEMM  Hs[M,N] = (A[M,K] @ W[K,N]) * dinv[row]
__global__ __launch_bounds__(256) void gemm128_kernel(const float* __restrict__ A,
                                                      const float* __restrict__ W,
                                                      const float* __restrict__ dinv,
                                                      float* __restrict__ C,
                                                      int M, int N, int K) {
    __shared__ float As[16][132];
    __shared__ float Bs[16][132];
    const int bm = blockIdx.x * 128;
    const int bn = blockIdx.y * 128;
    const int tid = threadIdx.x;
    const int tx = tid & 15, ty = tid >> 4;

    const int arow = tid >> 1;          // 0..127
    const int ak   = (tid & 1) * 8;     // 0 or 8
    const int brow = tid >> 5;          // 0..7
    const int bc4  = (tid & 31) * 4;    // 0..124

    float acc[2][2][4][4] = {};

    for (int k0 = 0; k0 < K; k0 += 16) {
        {   // stage A (transpose to [k][m])
            const float* ap = A + (size_t)(bm + arow) * K + k0 + ak;
            float4 a0 = {0,0,0,0}, a1 = {0,0,0,0};
            if (k0 + ak < K)     a0 = *reinterpret_cast<const float4*>(ap);
            if (k0 + ak + 4 < K) a1 = *reinterpret_cast<const float4*>(ap + 4);
            As[ak + 0][arow] = a0.x; As[ak + 1][arow] = a0.y;
            As[ak + 2][arow] = a0.z; As[ak + 3][arow] = a0.w;
            As[ak + 4][arow] = a1.x; As[ak + 5][arow] = a1.y;
            As[ak + 6][arow] = a1.z; As[ak + 7][arow] = a1.w;
        }
        {   // stage B
            float4 b0 = {0,0,0,0}, b1 = {0,0,0,0};
            if (k0 + brow < K)
                b0 = *reinterpret_cast<const float4*>(W + (size_t)(k0 + brow) * N + bn + bc4);
            if (k0 + brow + 8 < K)
                b1 = *reinterpret_cast<const float4*>(W + (size_t)(k0 + brow + 8) * N + bn + bc4);
            *reinterpret_cast<float4*>(&Bs[brow][bc4])     = b0;
            *reinterpret_cast<float4*>(&Bs[brow + 8][bc4]) = b1;
        }
        __syncthreads();
#pragma unroll
        for (int k = 0; k < 16; k++) {
            float4 a0 = *reinterpret_cast<const float4*>(&As[k][ty * 4]);
            float4 a1 = *reinterpret_cast<const float4*>(&As[k][64 + ty * 4]);
            float4 b0 = *reinterpret_cast<const float4*>(&Bs[k][tx * 4]);
            float4 b1 = *reinterpret_cast<const float4*>(&Bs[k][64 + tx * 4]);
            const float av[2][4] = {{a0.x, a0.y, a0.z, a0.w}, {a1.x, a1.y, a1.z, a1.w}};
            const float bv[2][4] = {{b0.x, b0.y, b0.z, b0.w}, {b1.x, b1.y, b1.z, b1.w}};
#pragma unroll
            for (int qi = 0; qi < 2; qi++)
#pragma unroll
                for (int qj = 0; qj < 2; qj++)
#pragma unroll
                    for (int i = 0; i < 4; i++)
#pragma unroll
                        for (int j = 0; j < 4; j++)
                            acc[qi][qj][i][j] += av[qi][i] * bv[qj][j];
        }
        __syncthreads();
    }
#pragma unroll
    for (int qi = 0; qi < 2; qi++)
#pragma unroll
        for (int i = 0; i < 4; i++) {
            int row = bm + qi * 64 + ty * 4 + i;
            float dv = dinv[row];
#pragma unroll
            for (int qj = 0; qj < 2; qj++) {
                float4 o = {acc[qi][qj][i][0] * dv, acc[qi][qj][i][1] * dv,
                            acc[qi][qj][i][2] * dv, acc[qi][qj][i][3] * dv};
                *reinterpret_cast<float4*>(&C[(size_t)row * N + bn + qj * 64 + tx * 4]) = o;
            }
        }
}

// ---------------------------------------------------------------- CSR gather
// out = dinv[v] * (Hs[v] + sum Hs[src]) + b     (Hs already row-scaled)
template <int D4>   // 32 (D=128) or 64 (D=256)
__global__ __launch_bounds__(256) void gather_kernel(
        const float* __restrict__ hs, const int* __restrict__ cnt,
        const int* __restrict__ offs, const float* __restrict__ dinv,
        const int* __restrict__ csr_src, const float* __restrict__ b,
        float* __restrict__ out, int n, int bpg) {
    constexpr int NPB = 256 / D4;
    int bid   = blockIdx.x;
    int xcd   = bid & 7;
    int slot  = bid >> 3;
    int graph = xcd + 8 * (slot / bpg);
    int local = slot % bpg;
    int vb    = graph * bpg + local;

    int v  = vb * NPB + threadIdx.x / D4;
    int f4 = threadIdx.x % D4;
    if (v >= n) return;
    const float4* h4 = reinterpret_cast<const float4*>(hs);
    int st = offs[v];
    int c  = cnt[v];
    float4 acc = h4[(size_t)v * D4 + f4];        // self term
    int j = 0;
    for (; j + 4 <= c; j += 4) {
        int s0 = csr_src[st + j],     s1 = csr_src[st + j + 1];
        int s2 = csr_src[st + j + 2], s3 = csr_src[st + j + 3];
        float4 h0 = h4[(size_t)s0 * D4 + f4];
        float4 h1 = h4[(size_t)s1 * D4 + f4];
        float4 h2 = h4[(size_t)s2 * D4 + f4];
        float4 h3 = h4[(size_t)s3 * D4 + f4];
        acc.x += h0.x + h1.x + h2.x + h3.x;
        acc.y += h0.y + h1.y + h2.y + h3.y;
        acc.z += h0.z + h1.z + h2.z + h3.z;
        acc.w += h0.w + h1.w + h2.w + h3.w;
    }
    for (; j < c; j++) {
        int s0 = csr_src[st + j];
        float4 h0 = h4[(size_t)s0 * D4 + f4];
        acc.x += h0.x; acc.y += h0.y; acc.z += h0.z; acc.w += h0.w;
    }
    float dv = dinv[v];
    float4 bb = reinterpret_cast<const float4*>(b)[f4];
    float4 o;
    o.x = acc.x * dv + bb.x;
    o.y = acc.y * dv + bb.y;
    o.z = acc.z * dv + bb.z;
    o.w = acc.w * dv + bb.w;
    reinterpret_cast<float4*>(out)[(size_t)v * D4 + f4] = o;
}

// ---------------------------------------------------------------- graphnorm partial sums (slot writes, no atomics)
template <int D4>   // 32 or 64
__global__ __launch_bounds__(256) void gn_partial_kernel(
        const float* __restrict__ x, float* __restrict__ sum1, float* __restrict__ sum2,
        int n_per) {
    constexpr int GROUPS = 256 / D4;
    __shared__ float4 l1[256];
    __shared__ float4 l2[256];
    int g = blockIdx.x >> 3;          // graph
    int ch = blockIdx.x & 7;          // node chunk (8 chunks)
    int f4 = threadIdx.x % D4;
    int grp = threadIdx.x / D4;
    int chunk = n_per / 8;
    int base = g * n_per + ch * chunk;
    const float4* x4 = reinterpret_cast<const float4*>(x);
    float4 s1 = {0.f, 0.f, 0.f, 0.f}, s2 = {0.f, 0.f, 0.f, 0.f};
    for (int i = grp; i < chunk; i += GROUPS) {
        float4 v = x4[(size_t)(base + i) * D4 + f4];
        s1.x += v.x; s1.y += v.y; s1.z += v.z; s1.w += v.w;
        s2.x += v.x * v.x; s2.y += v.y * v.y; s2.z += v.z * v.z; s2.w += v.w * v.w;
    }
    int t = threadIdx.x;
    l1[t] = s1; l2[t] = s2;
    __syncthreads();
    for (int str = 128; str >= D4; str >>= 1) {
        if (t < str) {
            float4 a = l1[t + str], b2 = l2[t + str];
            l1[t].x += a.x; l1[t].y += a.y; l1[t].z += a.z; l1[t].w += a.w;
            l2[t].x += b2.x; l2[t].y += b2.y; l2[t].z += b2.z; l2[t].w += b2.w;
        }
        __syncthreads();
    }
    if (t < D4) {
        size_t slot = (size_t)(g * 8 + ch) * (D4 * 4) + t * 4;
        *reinterpret_cast<float4*>(&sum1[slot]) = l1[t];
        *reinterpret_cast<float4*>(&sum2[slot]) = l2[t];
    }
}

__global__ void gn_final_kernel(const float* __restrict__ sum1, const float* __restrict__ sum2,
                                const float* __restrict__ ms, const float* __restrict__ w,
                                float* __restrict__ cmean, float* __restrict__ srw,
                                int n_per, int D, int total) {
    int t = blockIdx.x * blockDim.x + threadIdx.x;
    if (t >= total) return;
    int g = t / D;
    int f = t % D;
    float s1 = 0.f, s2 = 0.f;
    for (int ch = 0; ch < 8; ch++) {
        size_t slot = (size_t)(g * 8 + ch) * D + f;
        s1 += sum1[slot];
        s2 += sum2[slot];
    }
    float inv_n = 1.0f / (float)n_per;
    float mean = s1 * inv_n;
    float ex2  = s2 * inv_n;
    float m = ms[f];
    float var = ex2 - 2.f * m * mean * mean + m * m * mean * mean;
    cmean[t] = m * mean;
    srw[t]   = w[f] * rsqrtf(var + GN_EPS);
}

// ---------------------------------------------------------------- 1/||p|| for all 3 layers in one launch
__global__ void pnorm3_kernel(const float* __restrict__ p0, const float* __restrict__ p1,
                              const float* __restrict__ p2, int d0, int d1, int d2,
                              float* __restrict__ out) {
    __shared__ float red[256];
    const float* p = (blockIdx.x == 0) ? p0 : (blockIdx.x == 1) ? p1 : p2;
    int d          = (blockIdx.x == 0) ? d0 : (blockIdx.x == 1) ? d1 : d2;
    int t = threadIdx.x;
    float v = (t < d) ? p[t] : 0.0f;
    red[t] = v * v;
    __syncthreads();
    for (int s = 128; s; s >>= 1) {
        if (t < s) red[t] += red[t + s];
        __syncthreads();
    }
    if (t == 0) out[blockIdx.x] = 1.0f / sqrtf(red[0]);
}

// ---------------------------------------------------------------- graphnorm apply + relu + score
template <int DO>
__global__ __launch_bounds__(256) void gn_apply_score_kernel(
        float* __restrict__ x, const float* __restrict__ cmean, const float* __restrict__ srw,
        const float* __restrict__ bias, const float* __restrict__ p,
        const float* __restrict__ pinv, float* __restrict__ score, int n_per) {
    constexpr int V = DO / 64;
    int node = blockIdx.x * 4 + (threadIdx.x >> 6);
    int lane = threadIdx.x & 63;
    int g = node / n_per;
    float*       xr = x + (size_t)node * DO + lane * V;
    const float* cm = cmean + g * DO + lane * V;
    const float* sw = srw + g * DO + lane * V;
    const float* bb = bias + lane * V;
    const float* pp = p + lane * V;
    float dot = 0.f;
#pragma unroll
    for (int i = 0; i < V; i++) {
        float y = (xr[i] - cm[i]) * sw[i] + bb[i];
        y = fmaxf(y, 0.0f);
        xr[i] = y;
        dot += y * pp[i];
    }
#pragma unroll
    for (int off = 32; off; off >>= 1) dot += __shfl_xor(dot, off);
    if (lane == 0) score[node] = tanhf(dot * pinv[0]);
}

// ---------------------------------------------------------------- top-k via radix select
// Exact same SET as lax.top_k (score desc, index asc ties); enumeration is
// index-ascending (downstream ops are permutation-invariant within a graph).
// Deterministic: no global/order-dependent atomics.
template <int N, int K>
__global__ __launch_bounds__(1024) void topk_radix_kernel(
        const float* __restrict__ score, int* __restrict__ mapping,
        int* __restrict__ inv) {
    __shared__ int hist[256];
    __shared__ int sscan[N];
    __shared__ int sbyte, sneed;
    const int g = blockIdx.x;
    const int t = threadIdx.x;       // blockDim == N
    float sc = score[g * N + t];
    unsigned u = __float_as_uint(sc);
    unsigned key = (u & 0x80000000u) ? ~u : (u | 0x80000000u);   // monotone

    unsigned prefix = 0;
    int need = K;
#pragma unroll
    for (int shift = 24; shift >= 0; shift -= 8) {
        if (t < 256) hist[t] = 0;
        __syncthreads();
        unsigned hm = (shift == 24) ? 0u : (0xFFFFFFFFu << (shift + 8));
        if ((key & hm) == (prefix & hm))
            atomicAdd(&hist[(key >> shift) & 255], 1);
        __syncthreads();
        if (t < 256) sscan[t] = hist[t];
        __syncthreads();
        // suffix sums: sscan[b] = # matched keys with byte >= b
        for (int d = 1; d < 256; d <<= 1) {
            int x = (t < 256 && t + d < 256) ? sscan[t + d] : 0;
            __syncthreads();
            if (t < 256) sscan[t] += x;
            __syncthreads();
        }
        if (t < 256) {
            int ge  = sscan[t];
            int gt_ = (t + 1 < 256) ? sscan[t + 1] : 0;
            if (ge >= need && gt_ < need) { sbyte = t; sneed = need - gt_; }
        }
        __syncthreads();
        prefix |= ((unsigned)sbyte << shift);
        need = sneed;
        __syncthreads();
    }
    // prefix == exact k-th largest key; need == # ties to keep (lowest index first)
    bool gt = key > prefix;
    bool eq = (key == prefix);
    sscan[t] = (gt ? (1 << 16) : 0) | (eq ? 1 : 0);
    __syncthreads();
    for (int d = 1; d < N; d <<= 1) {
        int x = (t >= d) ? sscan[t - d] : 0;
        __syncthreads();
        sscan[t] += x;
        __syncthreads();
    }
    int incl   = sscan[t];
    int gtrank = (incl >> 16) - (gt ? 1 : 0);
    int eqrank = (incl & 0xFFFF) - (eq ? 1 : 0);
    int cntGT  = K - need;
    bool sel = gt || (eq && (eqrank < need));
    int old_g = g * N + t;
    if (sel) {
        int slot = gt ? gtrank : (cntGT + eqrank);
        mapping[old_g] = g * K + slot;
        inv[g * K + slot] = old_g;
    } else {
        mapping[old_g] = -1;
    }
}

// ---------------------------------------------------------------- permute + scale by score
__global__ void permute_scale_kernel(const float* __restrict__ x, const int* __restrict__ inv,
                                     const float* __restrict__ score, float* __restrict__ xn,
                                     int total, int ldof4) {
    int t = blockIdx.x * blockDim.x + threadIdx.x;
    if (t >= total) return;
    int node = t >> ldof4;
    int f4   = t & ((1 << ldof4) - 1);
    int dof4 = 1 << ldof4;
    int old = inv[node];
    float sc = score[old];
    float4 v = reinterpret_cast<const float4*>(x)[(size_t)old * dof4 + f4];
    float4 o = {v.x * sc, v.y * sc, v.z * sc, v.w * sc};
    reinterpret_cast<float4*>(xn)[t] = o;
}

// ---------------------------------------------------------------- final mean/max pool (1024 thr, 4-chunk)
__global__ __launch_bounds__(1024) void pool_kernel(const float* __restrict__ x,
                                                    float* __restrict__ out, int n_per) {
    __shared__ float ssum[1024];
    __shared__ float smax[1024];
    int g = blockIdx.x;
    int f = threadIdx.x & 255;
    int ch = threadIdx.x >> 8;       // 0..3
    const float* xg = x + (size_t)g * n_per * 256;
    float s = 0.f, mx = -INFINITY;
    for (int i = ch; i < n_per; i += 4) {
        float v = xg[(size_t)i * 256 + f];
        s += v;
        mx = fmaxf(mx, v);
    }
    ssum[threadIdx.x] = s;
    smax[threadIdx.x] = mx;
    __syncthreads();
    if (ch == 0) {
#pragma unroll
        for (int c = 1; c < 4; c++) {
            s  += ssum[f + c * 256];
            mx  = fmaxf(mx, smax[f + c * 256]);
        }
        out[g * 512 + f]       = s / (float)n_per;
        out[g * 512 + 256 + f] = mx;
    }
}

// ================================================================ host
static inline int cdiv_h(int a, int b) { return (a + b - 1) / b; }

extern "C" void kernel_launch(void* const* d_in, const int* in_sizes, int n_in,
                              void* d_out, int out_size, void* d_ws, size_t ws_size,
                              hipStream_t stream) {
    (void)in_sizes; (void)n_in; (void)out_size; (void)ws_size;

    const float* x_in = (const float*)d_in[0];
    const int*   ei   = (const int*)d_in[1];
    // d_in[2] = batch (unused, equal-sized graphs)
    const float* Wm[3]  = {(const float*)d_in[3],  (const float*)d_in[9],  (const float*)d_in[15]};
    const float* bv[3]  = {(const float*)d_in[4],  (const float*)d_in[10], (const float*)d_in[16]};
    const float* gnw[3] = {(const float*)d_in[5],  (const float*)d_in[11], (const float*)d_in[17]};
    const float* gnb[3] = {(const float*)d_in[6],  (const float*)d_in[12], (const float*)d_in[18]};
    const float* gnm[3] = {(const float*)d_in[7],  (const float*)d_in[13], (const float*)d_in[19]};
    const float* pv[3]  = {(const float*)d_in[8],  (const float*)d_in[14], (const float*)d_in[20]};

    // workspace carve
    size_t off = 0;
    auto alloc = [&](size_t bytes) {
        void* p = (char*)d_ws + off;
        off += (bytes + 255) & ~(size_t)255;
        return p;
    };
    float* X1      = (float*)alloc((size_t)65536 * 128 * 4);
    float* H       = (float*)alloc((size_t)65536 * 128 * 4);   // Hs (row-scaled)
    float* X2      = (float*)alloc((size_t)32768 * 128 * 4);
    int*   csr_src = (int*)alloc((size_t)ETOT * 4);
    int*   cmap    = (int*)alloc(NTOT * 4);
    int*   cnt     = (int*)alloc(65536 * 4);
    int*   offs    = (int*)alloc(65536 * 4);
    float* dinv    = (float*)alloc(65536 * 4);
    float* score   = (float*)alloc(65536 * 4);
    int*   mapping = (int*)alloc(65536 * 4);
    int*   inv     = (int*)alloc(32768 * 4);
    float* sum1    = (float*)alloc(64 * 8 * 256 * 4);   // per-chunk slots
    float* sum2    = (float*)alloc(64 * 8 * 256 * 4);
    float* cmean   = (float*)alloc(64 * 256 * 4);
    float* srw     = (float*)alloc(64 * 256 * 4);
    float* pinv    = (float*)alloc(256);

    const int nper[4] = {1024, 512, 256, 128};
    const int din[3]  = {100, 128, 128};
    const int dof[3]  = {128, 128, 256};

    cmap_init_kernel<<<NTOT / 256, 256, 0, stream>>>(cmap);
    pnorm3_kernel<<<3, 256, 0, stream>>>(pv[0], pv[1], pv[2], dof[0], dof[1], dof[2], pinv);

    for (int L = 0; L < 3; L++) {
        const int n    = NB * nper[L];
        const int k    = nper[L + 1];
        const int nn   = NB * k;
        const int D    = dof[L];
        const int dof4 = D / 4;
        const int ldof4 = (dof4 == 32) ? 5 : 6;
        const float* xin = (L == 0) ? x_in : X2;

        // ---- fused CSR build from original edges + cmap
        if (nper[L] == 1024)
            csr_build_kernel<1024><<<NB, 1024, 0, stream>>>(ei, cmap, cnt, offs, dinv, csr_src);
        else if (nper[L] == 512)
            csr_build_kernel<512><<<NB, 1024, 0, stream>>>(ei, cmap, cnt, offs, dinv, csr_src);
        else
            csr_build_kernel<256><<<NB, 1024, 0, stream>>>(ei, cmap, cnt, offs, dinv, csr_src);

        // ---- Hs = (x @ W) * dinv[row]
        gemm128_kernel<<<dim3(n / 128, D / 128), 256, 0, stream>>>(xin, Wm[L], dinv, H,
                                                                   n, D, din[L]);

        // ---- fused aggregate: X1 = dinv*(Hs[v] + sum Hs[src]) + b
        if (dof4 == 32) {
            const int NPB = 8;
            const int bpg = nper[L] / NPB;
            gather_kernel<32><<<n / NPB, 256, 0, stream>>>(H, cnt, offs, dinv, csr_src,
                                                           bv[L], X1, n, bpg);
        } else {
            const int NPB = 4;
            const int bpg = nper[L] / NPB;
            gather_kernel<64><<<n / NPB, 256, 0, stream>>>(H, cnt, offs, dinv, csr_src,
                                                           bv[L], X1, n, bpg);
        }

        // ---- graphnorm stats
        if (dof4 == 32)
            gn_partial_kernel<32><<<NB * 8, 256, 0, stream>>>(X1, sum1, sum2, nper[L]);
        else
            gn_partial_kernel<64><<<NB * 8, 256, 0, stream>>>(X1, sum1, sum2, nper[L]);
        gn_final_kernel<<<cdiv_h(NB * D, 256), 256, 0, stream>>>(sum1, sum2, gnm[L], gnw[L],
                                                                 cmean, srw, nper[L], D, NB * D);
        if (D == 128)
            gn_apply_score_kernel<128><<<n / 4, 256, 0, stream>>>(X1, cmean, srw, gnb[L],
                                                                  pv[L], pinv + L, score, nper[L]);
        else
            gn_apply_score_kernel<256><<<n / 4, 256, 0, stream>>>(X1, cmean, srw, gnb[L],
                                                                  pv[L], pinv + L, score, nper[L]);

        // ---- top-k pooling (radix select)
        if (nper[L] == 1024)
            topk_radix_kernel<1024, 512><<<NB, 1024, 0, stream>>>(score, mapping, inv);
        else if (nper[L] == 512)
            topk_radix_kernel<512, 256><<<NB, 512, 0, stream>>>(score, mapping, inv);
        else
            topk_radix_kernel<256, 128><<<NB, 256, 0, stream>>>(score, mapping, inv);

        permute_scale_kernel<<<cdiv_h(nn * dof4, 256), 256, 0, stream>>>(X1, inv, score, X2,
                                                                         nn * dof4, ldof4);
        if (L < 2)
            compose_map_kernel<<<NTOT / 256, 256, 0, stream>>>(cmap, mapping);
    }

    // final mean/max pool -> [64, 512]
    pool_kernel<<<NB, 1024, 0, stream>>>(X2, (float*)d_out, nper[3]);
}